// Round 4
// baseline (10955.637 us; speedup 1.0000x reference)
//
#include <hip/hip_runtime.h>
#include <math.h>

#define NN 100000
#define NE 1600000
#define NP 500000
#define KHOPS 6
#define NCHK 16384   // node/edge chunk rows; sized to fit dead fixed regions

typedef unsigned short u16;

__device__ __forceinline__ float gelu_erf(float x) {
    return 0.5f * x * (1.0f + erff(x * 0.70710678118654752f));
}
__device__ __forceinline__ float b2f(u16 u) {
    return __uint_as_float(((unsigned int)u) << 16);
}
__device__ __forceinline__ u16 f2b(float f) {
    unsigned int x = __float_as_uint(f);
    return (u16)((x + 0x7FFFu + ((x >> 16) & 1u)) >> 16);
}

// ---------------- column statistics (optionally weighted by up to 2 int count vectors)
template<int BF>
__global__ void col_stats(const void* __restrict__ Matv, int rows, int lc,
                          const int* __restrict__ w0, const int* __restrict__ w1,
                          float* __restrict__ sums, float* __restrict__ sumsq,
                          int base0, int base1)
{
    __shared__ float red[256];
    const int t = threadIdx.x;
    const int C = 1 << lc;
    const long total = (long)rows << lc;
    const long stride = (long)gridDim.x * 256;
    float s0 = 0.f, q0 = 0.f, s1 = 0.f, q1 = 0.f;
    for (long idx = (long)blockIdx.x * 256 + t; idx < total; idx += stride) {
        int r = (int)(idx >> lc);
        float v = BF ? b2f(((const u16*)Matv)[idx]) : ((const float*)Matv)[idx];
        float f0 = w0 ? (float)w0[r] : 1.0f;
        s0 += f0 * v;
        q0 += f0 * v * v;
        if (w1) {
            float f1 = (float)w1[r];
            s1 += f1 * v;
            q1 += f1 * v * v;
        }
    }
    red[t] = s0; __syncthreads();
    if (t < C) { float x = 0.f; for (int k = t; k < 256; k += C) x += red[k]; atomicAdd(&sums[base0 + t], x); }
    __syncthreads();
    red[t] = q0; __syncthreads();
    if (t < C) { float x = 0.f; for (int k = t; k < 256; k += C) x += red[k]; atomicAdd(&sumsq[base0 + t], x); }
    __syncthreads();
    if (w1) {
        red[t] = s1; __syncthreads();
        if (t < C) { float x = 0.f; for (int k = t; k < 256; k += C) x += red[k]; atomicAdd(&sums[base1 + t], x); }
        __syncthreads();
        red[t] = q1; __syncthreads();
        if (t < C) { float x = 0.f; for (int k = t; k < 256; k += C) x += red[k]; atomicAdd(&sumsq[base1 + t], x); }
    }
}

__global__ void bn_finalize(const float* __restrict__ sums, const float* __restrict__ sumsq,
                            const float* __restrict__ g, const float* __restrict__ b,
                            float* __restrict__ s, float* __restrict__ t,
                            int C, float count, float eps)
{
    int c = blockIdx.x * blockDim.x + threadIdx.x;
    if (c < C) {
        float mu = sums[c] / count;
        float var = sumsq[c] / count - mu * mu;
        float sc = g[c] * rsqrtf(var + eps);
        s[c] = sc;
        t[c] = b[c] - mu * sc;
    }
}

// x = gelu(x + bias[col]) in place, rows of 128 (fp32)
__global__ void gelu_bias(float* __restrict__ x, const float* __restrict__ bias, int n4)
{
    int stride = gridDim.x * blockDim.x;
    for (int i = blockIdx.x * blockDim.x + threadIdx.x; i < n4; i += stride) {
        int c4 = (i & 31) * 4;
        float4 v = ((const float4*)x)[i];
        v.x = gelu_erf(v.x + bias[c4 + 0]);
        v.y = gelu_erf(v.y + bias[c4 + 1]);
        v.z = gelu_erf(v.z + bias[c4 + 2]);
        v.w = gelu_erf(v.w + bias[c4 + 3]);
        ((float4*)x)[i] = v;
    }
}

__global__ void hist_add(const int* __restrict__ idx, int n, int* __restrict__ cnt)
{
    int stride = gridDim.x * blockDim.x;
    for (int i = blockIdx.x * blockDim.x + threadIdx.x; i < n; i += stride)
        atomicAdd(&cnt[idx[i]], 1);
}

__global__ void make_dinv(const int* __restrict__ cnt, float* __restrict__ dinv, int n)
{
    int i = blockIdx.x * blockDim.x + threadIdx.x;
    if (i < n) {
        int c = cnt[i];
        dinv[i] = (c > 0) ? rsqrtf((float)c) : 0.f;
    }
}

// single-block strip exclusive scan; out[n] = total
__global__ void exscan1024(const int* __restrict__ in, int* __restrict__ out, int n)
{
    __shared__ int buf[1024];
    int t = threadIdx.x;
    int per = (n + 1023) >> 10;
    int s0 = t * per; if (s0 > n) s0 = n;
    int s1 = s0 + per; if (s1 > n) s1 = n;
    int sum = 0;
    for (int i = s0; i < s1; ++i) sum += in[i];
    buf[t] = sum;
    __syncthreads();
    int incl = sum;
    for (int o = 1; o < 1024; o <<= 1) {
        int tmp = (t >= o) ? buf[t - o] : 0;
        __syncthreads();
        incl += tmp;
        buf[t] = incl;
        __syncthreads();
    }
    int run = incl - sum;
    for (int i = s0; i < s1; ++i) { out[i] = run; run += in[i]; }
    if (t == 1023) out[n] = run;
}

__global__ void csr_build(const int* __restrict__ src, const int* __restrict__ dst, int n,
                          const int* __restrict__ indptr, int* __restrict__ cursor,
                          int* __restrict__ csrS)
{
    int stride = gridDim.x * blockDim.x;
    for (int e = blockIdx.x * blockDim.x + threadIdx.x; e < n; e += stride) {
        int s = src[e], d = dst[e];
        int pos = indptr[d] + atomicAdd(&cursor[d], 1);
        csrS[pos] = s;
    }
}

// hout[n,:] = sum_e dinv[s]*dinv[n]*hin[s,:]  (bf16 storage, fp32 accumulate)
__global__ void spmm_hop(const u16* __restrict__ hin, u16* __restrict__ hout,
                         const int* __restrict__ indptr, const int* __restrict__ csrS,
                         const float* __restrict__ dinv)
{
    int gid = blockIdx.x * blockDim.x + threadIdx.x;
    int node = gid >> 6;
    int lane = gid & 63;
    if (node >= NN) return;
    float dn = dinv[node];
    int beg = indptr[node], end = indptr[node + 1];
    float a0 = 0.f, a1 = 0.f;
    for (int e = beg; e < end; ++e) {
        int s = csrS[e];
        float wv = dn * dinv[s];
        const u16* row = hin + (size_t)s * 128;
        a0 = fmaf(wv, b2f(row[lane]), a0);
        a1 = fmaf(wv, b2f(row[lane + 64]), a1);
    }
    size_t o = (size_t)node * 128;
    hout[o + lane] = f2b(a0);
    hout[o + lane + 64] = f2b(a1);
}

// W0p[k,j] = s[k]*W0[k,j]
__global__ void fold_w(const float* __restrict__ W0, const float* __restrict__ s,
                       float* __restrict__ Wp)
{
    int i = blockIdx.x * blockDim.x + threadIdx.x;
    if (i < 544 * 512) {
        int k = i >> 9;
        Wp[i] = s[k] * W0[i];
    }
}

// b0p[j] = b0[j] + sum_k t[k]*W0[k,j]
__global__ void fold_b(const float* __restrict__ W0, const float* __restrict__ b0,
                       const float* __restrict__ tv, float* __restrict__ bp)
{
    int j = blockIdx.x * blockDim.x + threadIdx.x;
    if (j < 512) {
        float s = b0[j];
        for (int k = 0; k < 544; ++k) s = fmaf(tv[k], W0[k * 512 + j], s);
        bp[j] = s;
    }
}

// ------------- tiled fp32 GEMM, tile 64x128, KT=32
// AMODE 0: dense f32 A0, lda
// AMODE 1: dense bf16 A0, row stride 128
// AMODE 2: edge Omega gather [aEmb(bf16)[i0] | aEmb[i1] | X(f32)[i0] | X[i1] | Y]
// AMODE 3: BN-on-the-fly f32: A = A0*sv + tv, row stride 128
// AMODE 4: concat [BN(A0,128) | f32 A1 (stride 128)], Kd=256
// ACT 1: bias+gelu. ACCUM: C += (only OUTBF=0). OUTBF: store bf16.
template<int AMODE, int ACT, int ACCUM, int OUTBF>
__launch_bounds__(256, 2)
__global__ void gemm_k(const void* __restrict__ A0v, const void* __restrict__ A1v,
                       const float* __restrict__ Yp,
                       const int* __restrict__ I0, const int* __restrict__ I1,
                       int rowOffset,
                       const float* __restrict__ sv, const float* __restrict__ tv,
                       const float* __restrict__ W, const float* __restrict__ bias,
                       void* __restrict__ Cv, int Mr, int Kd, int Nc, int lda)
{
    __shared__ __align__(16) float As[32][68];
    __shared__ __align__(16) float Bs[32][128];
    __shared__ int i0s[64], i1s[64];

    const int t = threadIdx.x;
    const int row0 = blockIdx.x * 64;
    const int colb = blockIdx.y * 128;

    if (AMODE == 2) {
        if (t < 64) {
            int r = row0 + t;
            i0s[t] = (r < Mr) ? I0[rowOffset + r] : 0;
        } else if (t < 128) {
            int r = row0 + (t - 64);
            i1s[t - 64] = (r < Mr) ? I1[rowOffset + r] : 0;
        }
    }

    float acc[8][4];
#pragma unroll
    for (int i = 0; i < 8; ++i)
#pragma unroll
        for (int j = 0; j < 4; ++j) acc[i][j] = 0.f;

    const int r0 = (t >> 5) << 3;
    const int c0 = (t & 31) << 2;

    for (int k0 = 0; k0 < Kd; k0 += 32) {
        __syncthreads();   // covers i0s/i1s on first iter + As/Bs reuse after
#pragma unroll
        for (int i = 0; i < 8; ++i) {
            int idx = i * 256 + t;
            int r = idx >> 5, kk = idx & 31;
            int row = row0 + r;
            float v = 0.f;
            if (row < Mr) {
                if (AMODE == 0) {
                    v = ((const float*)A0v)[(size_t)row * lda + k0 + kk];
                } else if (AMODE == 1) {
                    v = b2f(((const u16*)A0v)[(size_t)row * 128 + k0 + kk]);
                } else if (AMODE == 3) {
                    int c = k0 + kk;
                    v = ((const float*)A0v)[(size_t)row * 128 + c] * sv[c] + tv[c];
                } else if (AMODE == 4) {
                    int c = k0 + kk;
                    if (c < 128)
                        v = ((const float*)A0v)[(size_t)row * 128 + c] * sv[c] + tv[c];
                    else
                        v = ((const float*)A1v)[(size_t)row * 128 + c - 128];
                } else { // AMODE 2
                    int seg = k0 >> 7;
                    int cb = (k0 & 127) + kk;
                    if (seg == 0)      v = b2f(((const u16*)A0v)[(size_t)i0s[r] * 128 + cb]);
                    else if (seg == 1) v = b2f(((const u16*)A0v)[(size_t)i1s[r] * 128 + cb]);
                    else if (seg == 2) v = ((const float*)A1v)[(size_t)i0s[r] * 128 + cb];
                    else if (seg == 3) v = ((const float*)A1v)[(size_t)i1s[r] * 128 + cb];
                    else               v = Yp[(size_t)(rowOffset + row) * 32 + kk];
                }
            }
            As[kk][r] = v;
        }
#pragma unroll
        for (int i = 0; i < 16; ++i) {
            int idx = i * 256 + t;
            int kk = idx >> 7, c = idx & 127;
            Bs[kk][c] = W[(size_t)(k0 + kk) * Nc + colb + c];
        }
        __syncthreads();
#pragma unroll
        for (int kk = 0; kk < 32; ++kk) {
            float4 a0v = *(const float4*)&As[kk][r0];
            float4 a1v = *(const float4*)&As[kk][r0 + 4];
            float4 bv  = *(const float4*)&Bs[kk][c0];
            float ar[8] = {a0v.x, a0v.y, a0v.z, a0v.w, a1v.x, a1v.y, a1v.z, a1v.w};
            float br[4] = {bv.x, bv.y, bv.z, bv.w};
#pragma unroll
            for (int i = 0; i < 8; ++i)
#pragma unroll
                for (int j = 0; j < 4; ++j)
                    acc[i][j] = fmaf(ar[i], br[j], acc[i][j]);
        }
    }

#pragma unroll
    for (int i = 0; i < 8; ++i) {
        int row = row0 + r0 + i;
        if (row < Mr) {
            size_t off = (size_t)row * Nc + colb + c0;
            float v0 = acc[i][0], v1 = acc[i][1], v2 = acc[i][2], v3 = acc[i][3];
            if (ACCUM && !OUTBF) {
                float4 old = *(const float4*)((const float*)Cv + off);
                v0 += old.x; v1 += old.y; v2 += old.z; v3 += old.w;
            }
            if (ACT == 1) {
                v0 = gelu_erf(v0 + bias[colb + c0 + 0]);
                v1 = gelu_erf(v1 + bias[colb + c0 + 1]);
                v2 = gelu_erf(v2 + bias[colb + c0 + 2]);
                v3 = gelu_erf(v3 + bias[colb + c0 + 3]);
            }
            if (OUTBF) {
                ushort4 o;
                o.x = f2b(v0); o.y = f2b(v1); o.z = f2b(v2); o.w = f2b(v3);
                *(ushort4*)((u16*)Cv + off) = o;
            } else {
                float4 o = make_float4(v0, v1, v2, v3);
                *(float4*)((float*)Cv + off) = o;
            }
        }
    }
}

// logits = cl @ endW + endB ; softmax over 8 ; one wave per row
__global__ void node_head(const float* __restrict__ cl, const float* __restrict__ Wend,
                          const float* __restrict__ bend, float* __restrict__ out, int m)
{
    __shared__ float WsT[8 * 128];
    __shared__ float bs[8];
    int t = threadIdx.x;
    for (int i = t; i < 1024; i += 256) {
        int k = i >> 3, j = i & 7;
        WsT[j * 128 + k] = Wend[i];
    }
    if (t < 8) bs[t] = bend[t];
    __syncthreads();
    int gid = blockIdx.x * 256 + t;
    int wave = gid >> 6, lane = gid & 63;
    if (wave >= m) return;
    float v0 = cl[(size_t)wave * 128 + lane];
    float v1 = cl[(size_t)wave * 128 + lane + 64];
    float lg[8];
#pragma unroll
    for (int j = 0; j < 8; ++j) {
        float p = v0 * WsT[j * 128 + lane] + v1 * WsT[j * 128 + lane + 64];
#pragma unroll
        for (int o = 32; o; o >>= 1) p += __shfl_down(p, o);
        lg[j] = p;
    }
    if (lane == 0) {
        float mx = -1e30f;
#pragma unroll
        for (int j = 0; j < 8; ++j) { lg[j] += bs[j]; mx = fmaxf(mx, lg[j]); }
        float s = 0.f;
#pragma unroll
        for (int j = 0; j < 8; ++j) { lg[j] = expf(lg[j] - mx); s += lg[j]; }
        float inv = 1.f / s;
#pragma unroll
        for (int j = 0; j < 8; ++j) out[(size_t)wave * 8 + j] = lg[j] * inv;
    }
}

// e_pred = sigmoid(o2 @ elEW + b) ; one wave per row, K=256
__global__ void edge_head(const float* __restrict__ o2, const float* __restrict__ Wend,
                          const float* __restrict__ bend, float* __restrict__ out, int m)
{
    int gid = blockIdx.x * blockDim.x + threadIdx.x;
    int wave = gid >> 6, lane = gid & 63;
    if (wave >= m) return;
    float4 wv = *(const float4*)&Wend[lane * 4];
    float4 xv = *(const float4*)&o2[(size_t)wave * 256 + lane * 4];
    float p = xv.x * wv.x + xv.y * wv.y + xv.z * wv.z + xv.w * wv.w;
#pragma unroll
    for (int o = 32; o; o >>= 1) p += __shfl_down(p, o);
    if (lane == 0) out[wave] = 1.f / (1.f + expf(-(p + bend[0])));
}

extern "C" void kernel_launch(void* const* d_in, const int* in_sizes, int n_in,
                              void* d_out, int out_size, void* d_ws, size_t ws_size,
                              hipStream_t stream)
{
    const float* X    = (const float*)d_in[0];
    const float* Y    = (const float*)d_in[1];
    const int*   EI   = (const int*)d_in[2];
    const int*   I0   = (const int*)d_in[3];
    const int*   I1   = (const int*)d_in[4];
    const float* bnG  = (const float*)d_in[5];
    const float* bnB  = (const float*)d_in[6];
    const float* Wlin = (const float*)d_in[7];
    const float* blin = (const float*)d_in[8];
    const float* tagWs= (const float*)d_in[9];
    const float* tagB = (const float*)d_in[10];
    const float* nlW0 = (const float*)d_in[11];
    const float* nlb0 = (const float*)d_in[12];
    const float* nlW1 = (const float*)d_in[13];
    const float* nlb1 = (const float*)d_in[14];
    const float* clW  = (const float*)d_in[15];
    const float* clb  = (const float*)d_in[16];
    const float* endW = (const float*)d_in[17];
    const float* endB = (const float*)d_in[18];
    const float* beG  = (const float*)d_in[19];
    const float* beB  = (const float*)d_in[20];
    const float* elW0 = (const float*)d_in[21];
    const float* elb0 = (const float*)d_in[22];
    const float* elW1 = (const float*)d_in[23];
    const float* elb1 = (const float*)d_in[24];
    const float* elEW = (const float*)d_in[25];
    const float* elEb = (const float*)d_in[26];

    const int N = NN, E = NE, P = NP;

    char* w = (char*)d_ws;
    size_t off = 0;
    auto alloc = [&](size_t bytes) -> void* {
        void* p = w + off;
        off += (bytes + 255) & ~(size_t)255;
        return p;
    };

    // --- zeroed region (stats accumulators + counters), one memset ---
    size_t zeroBytes = (size_t)(544 + 544 + 128 + 128) * 4 + (size_t)4 * N * 4;
    char* zr = (char*)alloc(zeroBytes);
    float* statS = (float*)zr;
    float* statQ = statS + 544;
    float* nodeS = statQ + 544;
    float* nodeQ = nodeS + 128;
    int* cnt    = (int*)(nodeQ + 128);
    int* cursor = cnt + N;
    int* cnt0   = cursor + N;
    int* cnt1   = cnt0 + N;

    int*   indptr = (int*)alloc((size_t)(N + 1) * 4);
    float* dinv   = (float*)alloc((size_t)N * 4);
    int*   csrS   = (int*)alloc((size_t)E * 4);
    float* sNode  = (float*)alloc(128 * 4);
    float* tNode  = (float*)alloc(128 * 4);
    float* sEdge  = (float*)alloc(544 * 4);
    float* tEdge  = (float*)alloc(544 * 4);
    float* W0p    = (float*)alloc((size_t)544 * 512 * 4);
    float* b0p    = (float*)alloc(512 * 4);
    u16*   hA     = (u16*)alloc((size_t)N * 128 * 2);   // bf16; later = aEmb
    u16*   hB     = (u16*)alloc((size_t)N * 128 * 2);   // bf16; later = node chunk region
    float* outT   = (float*)alloc((size_t)N * 128 * 4); // fp32; later = edge chunk region

    if (ws_size < off) return;   // diagnostic: ref-vs-zeros absmax fail instead of a fault

    u16* aEmb = hA;                       // alias: hA dead after TAG
    float* nodeChunk = (float*)hB;        // alias: hB dead after TAG (a256 + clbuf)
    float* edgeChunk = outT;              // alias: outT dead after node-MLP L1 (o1 + o2)

    float* out_nodes = (float*)d_out;
    float* out_epred = (float*)d_out + (size_t)N * 8;

    hipMemsetAsync(zr, 0, zeroBytes, stream);

    // ---- node BN stats (X fp32) ----
    col_stats<0><<<1024, 256, 0, stream>>>(X, N, 7, nullptr, nullptr, nodeS, nodeQ, 0, 0);
    bn_finalize<<<1, 128, 0, stream>>>(nodeS, nodeQ, bnG, bnB, sNode, tNode, 128, (float)N, 1e-5f);

    // ---- tag linear: hA = bf16(gelu(BN(X) @ Wlin + blin)) ----
    dim3 g1((N + 63) / 64, 1);
    gemm_k<3, 1, 0, 1><<<g1, 256, 0, stream>>>(X, nullptr, nullptr, nullptr, nullptr, 0,
                                               sNode, tNode, Wlin, blin, hA, N, 128, 128, 128);

    // ---- graph prep ----
    hist_add<<<2048, 256, 0, stream>>>(EI + E, E, cnt);
    hist_add<<<1024, 256, 0, stream>>>(I0, P, cnt0);
    hist_add<<<1024, 256, 0, stream>>>(I1, P, cnt1);
    exscan1024<<<1, 1024, 0, stream>>>(cnt, indptr, N);
    make_dinv<<<(N + 255) / 256, 256, 0, stream>>>(cnt, dinv, N);
    csr_build<<<2048, 256, 0, stream>>>(EI, EI + E, E, indptr, cursor, csrS);

    // ---- TAGConv: outT(fp32) = sum_k S^k h @ Ws[k] ----
    gemm_k<1, 0, 0, 0><<<g1, 256, 0, stream>>>(hA, nullptr, nullptr, nullptr, nullptr, 0,
                                               nullptr, nullptr, tagWs, nullptr, outT, N, 128, 128, 128);
    u16* cur = hA; u16* nxt = hB;
    for (int k = 1; k <= KHOPS; ++k) {
        spmm_hop<<<(N * 64 + 255) / 256, 256, 0, stream>>>(cur, nxt, indptr, csrS, dinv);
        gemm_k<1, 0, 1, 0><<<g1, 256, 0, stream>>>(nxt, nullptr, nullptr, nullptr, nullptr, 0,
                                                   nullptr, nullptr, tagWs + (size_t)k * 128 * 128,
                                                   nullptr, outT, N, 128, 128, 128);
        u16* tmp = cur; cur = nxt; nxt = tmp;
    }
    gelu_bias<<<2048, 256, 0, stream>>>(outT, tagB, N * 128 / 4);

    // ---- node MLP: chunks live in hB (dead) ----
    for (int nb = 0; nb < N; nb += NCHK) {
        int m = (N - nb < NCHK) ? (N - nb) : NCHK;
        float* a256  = nodeChunk;                         // [NCHK,256] f32
        float* clbuf = nodeChunk + (size_t)NCHK * 256;    // [NCHK,128] f32
        dim3 gA((m + 63) / 64, 2);
        gemm_k<4, 1, 0, 0><<<gA, 256, 0, stream>>>(X + (size_t)nb * 128, outT + (size_t)nb * 128,
                                                   nullptr, nullptr, nullptr, 0,
                                                   sNode, tNode, nlW0, nlb0, a256, m, 256, 256, 0);
        dim3 gB((m + 63) / 64, 1);
        gemm_k<0, 1, 0, 1><<<gB, 256, 0, stream>>>(a256, nullptr, nullptr, nullptr, nullptr, 0,
                                                   nullptr, nullptr, nlW1, nlb1,
                                                   aEmb + (size_t)nb * 128, m, 256, 128, 256);
        gemm_k<1, 1, 0, 0><<<gB, 256, 0, stream>>>(aEmb + (size_t)nb * 128, nullptr, nullptr, nullptr, nullptr, 0,
                                                   nullptr, nullptr, clW, clb, clbuf, m, 128, 128, 128);
        node_head<<<(m + 3) / 4, 256, 0, stream>>>(clbuf, endW, endB, out_nodes + (size_t)nb * 8, m);
    }

    // ---- edge BN stats (count-weighted, exact vs the gathered bf16/f32 values) ----
    col_stats<1><<<1024, 256, 0, stream>>>(aEmb, N, 7, cnt0, cnt1, statS, statQ, 0, 128);
    col_stats<0><<<1024, 256, 0, stream>>>(X,    N, 7, cnt0, cnt1, statS, statQ, 256, 384);
    col_stats<0><<<1024, 256, 0, stream>>>(Y,    P, 5, nullptr, nullptr, statS, statQ, 512, 0);
    bn_finalize<<<3, 256, 0, stream>>>(statS, statQ, beG, beB, sEdge, tEdge, 544, (float)P, 1.0f);
    fold_w<<<(544 * 512 + 255) / 256, 256, 0, stream>>>(elW0, sEdge, W0p);
    fold_b<<<2, 256, 0, stream>>>(elW0, elb0, tEdge, b0p);

    // ---- edge MLP: chunks live in outT (dead) ----
    for (int pb = 0; pb < P; pb += NCHK) {
        int m = (P - pb < NCHK) ? (P - pb) : NCHK;
        float* o1 = edgeChunk;                          // [NCHK,512] f32
        float* o2 = edgeChunk + (size_t)NCHK * 512;     // [NCHK,256] f32
        dim3 gA((m + 63) / 64, 4);
        gemm_k<2, 1, 0, 0><<<gA, 256, 0, stream>>>(aEmb, X, Y, I0, I1, pb,
                                                   nullptr, nullptr, W0p, b0p, o1, m, 544, 512, 0);
        dim3 gB((m + 63) / 64, 2);
        gemm_k<0, 1, 0, 0><<<gB, 256, 0, stream>>>(o1, nullptr, nullptr, nullptr, nullptr, 0,
                                                   nullptr, nullptr, elW1, elb1, o2, m, 512, 256, 512);
        edge_head<<<(m + 3) / 4, 256, 0, stream>>>(o2, elEW, elEb, out_epred + pb, m);
    }
}

// Round 5
// 3864.406 us; speedup vs baseline: 2.8350x; 2.8350x over previous
//
#include <hip/hip_runtime.h>
#include <math.h>

#define NN 100000
#define NE 1600000
#define NP 500000
#define KHOPS 6
#define NCHK 24576

typedef unsigned short u16;
typedef short bf16x8 __attribute__((ext_vector_type(8)));
typedef float f32x4 __attribute__((ext_vector_type(4)));

__device__ __forceinline__ float gelu_erf(float x) {
    return 0.5f * x * (1.0f + erff(x * 0.70710678118654752f));
}
__device__ __forceinline__ float b2f(u16 u) {
    return __uint_as_float(((unsigned int)u) << 16);
}
__device__ __forceinline__ u16 f2b(float f) {
    unsigned int x = __float_as_uint(f);
    return (u16)((x + 0x7FFFu + ((x >> 16) & 1u)) >> 16);
}
__device__ __forceinline__ bf16x8 cvt8(float4 a, float4 b) {
    bf16x8 v;
    v[0]=(short)f2b(a.x); v[1]=(short)f2b(a.y); v[2]=(short)f2b(a.z); v[3]=(short)f2b(a.w);
    v[4]=(short)f2b(b.x); v[5]=(short)f2b(b.y); v[6]=(short)f2b(b.z); v[7]=(short)f2b(b.w);
    return v;
}

// ---------------- column statistics (optionally weighted by up to 2 int count vectors)
template<int BF>
__global__ void col_stats(const void* __restrict__ Matv, int rows, int lc,
                          const int* __restrict__ w0, const int* __restrict__ w1,
                          float* __restrict__ sums, float* __restrict__ sumsq,
                          int base0, int base1)
{
    __shared__ float red[256];
    const int t = threadIdx.x;
    const int C = 1 << lc;
    const long total = (long)rows << lc;
    const long stride = (long)gridDim.x * 256;
    float s0 = 0.f, q0 = 0.f, s1 = 0.f, q1 = 0.f;
    for (long idx = (long)blockIdx.x * 256 + t; idx < total; idx += stride) {
        int r = (int)(idx >> lc);
        float v = BF ? b2f(((const u16*)Matv)[idx]) : ((const float*)Matv)[idx];
        float f0 = w0 ? (float)w0[r] : 1.0f;
        s0 += f0 * v;
        q0 += f0 * v * v;
        if (w1) {
            float f1 = (float)w1[r];
            s1 += f1 * v;
            q1 += f1 * v * v;
        }
    }
    red[t] = s0; __syncthreads();
    if (t < C) { float x = 0.f; for (int k = t; k < 256; k += C) x += red[k]; atomicAdd(&sums[base0 + t], x); }
    __syncthreads();
    red[t] = q0; __syncthreads();
    if (t < C) { float x = 0.f; for (int k = t; k < 256; k += C) x += red[k]; atomicAdd(&sumsq[base0 + t], x); }
    __syncthreads();
    if (w1) {
        red[t] = s1; __syncthreads();
        if (t < C) { float x = 0.f; for (int k = t; k < 256; k += C) x += red[k]; atomicAdd(&sums[base1 + t], x); }
        __syncthreads();
        red[t] = q1; __syncthreads();
        if (t < C) { float x = 0.f; for (int k = t; k < 256; k += C) x += red[k]; atomicAdd(&sumsq[base1 + t], x); }
    }
}

__global__ void bn_finalize(const float* __restrict__ sums, const float* __restrict__ sumsq,
                            const float* __restrict__ g, const float* __restrict__ b,
                            float* __restrict__ s, float* __restrict__ t,
                            int C, float count, float eps)
{
    int c = blockIdx.x * blockDim.x + threadIdx.x;
    if (c < C) {
        float mu = sums[c] / count;
        float var = sumsq[c] / count - mu * mu;
        float sc = g[c] * rsqrtf(var + eps);
        s[c] = sc;
        t[c] = b[c] - mu * sc;
    }
}

// houtb = bf16(gelu(outT + bias[col])), rows of 128
__global__ void gelu_bias_bf(const float* __restrict__ x, const float* __restrict__ bias,
                             u16* __restrict__ out, int n4)
{
    int stride = gridDim.x * blockDim.x;
    for (int i = blockIdx.x * blockDim.x + threadIdx.x; i < n4; i += stride) {
        int c4 = (i & 31) * 4;
        float4 v = ((const float4*)x)[i];
        ushort4 o;
        o.x = f2b(gelu_erf(v.x + bias[c4 + 0]));
        o.y = f2b(gelu_erf(v.y + bias[c4 + 1]));
        o.z = f2b(gelu_erf(v.z + bias[c4 + 2]));
        o.w = f2b(gelu_erf(v.w + bias[c4 + 3]));
        ((ushort4*)out)[i] = o;
    }
}

__global__ void hist_add(const int* __restrict__ idx, int n, int* __restrict__ cnt)
{
    int stride = gridDim.x * blockDim.x;
    for (int i = blockIdx.x * blockDim.x + threadIdx.x; i < n; i += stride)
        atomicAdd(&cnt[idx[i]], 1);
}

__global__ void make_dinv(const int* __restrict__ cnt, float* __restrict__ dinv, int n)
{
    int i = blockIdx.x * blockDim.x + threadIdx.x;
    if (i < n) {
        int c = cnt[i];
        dinv[i] = (c > 0) ? rsqrtf((float)c) : 0.f;
    }
}

__global__ void exscan1024(const int* __restrict__ in, int* __restrict__ out, int n)
{
    __shared__ int buf[1024];
    int t = threadIdx.x;
    int per = (n + 1023) >> 10;
    int s0 = t * per; if (s0 > n) s0 = n;
    int s1 = s0 + per; if (s1 > n) s1 = n;
    int sum = 0;
    for (int i = s0; i < s1; ++i) sum += in[i];
    buf[t] = sum;
    __syncthreads();
    int incl = sum;
    for (int o = 1; o < 1024; o <<= 1) {
        int tmp = (t >= o) ? buf[t - o] : 0;
        __syncthreads();
        incl += tmp;
        buf[t] = incl;
        __syncthreads();
    }
    int run = incl - sum;
    for (int i = s0; i < s1; ++i) { out[i] = run; run += in[i]; }
    if (t == 1023) out[n] = run;
}

__global__ void csr_build(const int* __restrict__ src, const int* __restrict__ dst, int n,
                          const int* __restrict__ indptr, int* __restrict__ cursor,
                          int* __restrict__ csrS)
{
    int stride = gridDim.x * blockDim.x;
    for (int e = blockIdx.x * blockDim.x + threadIdx.x; e < n; e += stride) {
        int s = src[e], d = dst[e];
        int pos = indptr[d] + atomicAdd(&cursor[d], 1);
        csrS[pos] = s;
    }
}

__global__ void spmm_hop(const u16* __restrict__ hin, u16* __restrict__ hout,
                         const int* __restrict__ indptr, const int* __restrict__ csrS,
                         const float* __restrict__ dinv)
{
    int gid = blockIdx.x * blockDim.x + threadIdx.x;
    int node = gid >> 6;
    int lane = gid & 63;
    if (node >= NN) return;
    float dn = dinv[node];
    int beg = indptr[node], end = indptr[node + 1];
    float a0 = 0.f, a1 = 0.f;
    for (int e = beg; e < end; ++e) {
        int s = csrS[e];
        float wv = dn * dinv[s];
        const u16* row = hin + (size_t)s * 128;
        a0 = fmaf(wv, b2f(row[lane]), a0);
        a1 = fmaf(wv, b2f(row[lane + 64]), a1);
    }
    size_t o = (size_t)node * 128;
    hout[o + lane] = f2b(a0);
    hout[o + lane + 64] = f2b(a1);
}

// transpose + convert: out[n*K+k] = bf16(in[k*N+n])
__global__ void convT(const float* __restrict__ in, u16* __restrict__ out, int K, int Nc)
{
    int i = blockIdx.x * blockDim.x + threadIdx.x;
    if (i < K * Nc) {
        int n = i / K, k = i - n * K;
        out[i] = f2b(in[(size_t)k * Nc + n]);
    }
}

// W0pb[n*544+k] = bf16(s[k]*elW0[k*512+n])
__global__ void fold_wT(const float* __restrict__ W0, const float* __restrict__ s,
                        u16* __restrict__ out)
{
    int i = blockIdx.x * blockDim.x + threadIdx.x;
    if (i < 512 * 544) {
        int n = i / 544, k = i - n * 544;
        out[i] = f2b(s[k] * W0[(size_t)k * 512 + n]);
    }
}

__global__ void fold_b(const float* __restrict__ W0, const float* __restrict__ b0,
                       const float* __restrict__ tv, float* __restrict__ bp)
{
    int j = blockIdx.x * blockDim.x + threadIdx.x;
    if (j < 512) {
        float s = b0[j];
        for (int k = 0; k < 544; ++k) s = fmaf(tv[k], W0[k * 512 + j], s);
        bp[j] = s;
    }
}

// ------------- MFMA bf16 GEMM: C[M,Nc] = act(A @ W + bias), tile 128x128, BK=32
// 4 waves (2x2), each wave 64x64 = 4x4 frags of mfma_f32_16x16x32_bf16.
// B is pre-transposed bf16: Wb[n][k] (row n = output col, Kd elems).
// AMODE 0: dense bf16 A0, lda elems
// AMODE 1: concat [BN(fp32 A0, sv/tv) | bf16 A1], both row-stride 128, Kd=256
// AMODE 2: edge gather [aEmb(bf16)[i0]|aEmb[i1]|bf16(X f32)[i0]|[i1]|bf16(Y f32)], Kd=544
// AMODE 3: BN-on-the-fly from fp32 A0 (row stride 128)
// ACT 1: bias+gelu.  ACCUM: C += result (fp32 C only).  OUTBF: store bf16.
template<int AMODE, int ACT, int ACCUM, int OUTBF>
__launch_bounds__(256, 2)
__global__ void gemm_mfma(const void* __restrict__ A0v, const void* __restrict__ A1v,
                          const float* __restrict__ Yp,
                          const int* __restrict__ I0, const int* __restrict__ I1,
                          int rowOffset,
                          const float* __restrict__ sv, const float* __restrict__ tv,
                          const u16* __restrict__ Wb, const float* __restrict__ bias,
                          void* __restrict__ Cv, int Mr, int Kd, int Nc, int lda)
{
    __shared__ __align__(16) u16 As[128 * 32];
    __shared__ __align__(16) u16 Bs[128 * 32];
    __shared__ int i0s[128], i1s[128];

    const int t = threadIdx.x;
    const int lane = t & 63;
    const int wid = t >> 6;
    const int wm = wid >> 1, wn = wid & 1;
    const int lb = lane & 15, lh = lane >> 4;
    const int row0 = blockIdx.x * 128;
    const int colb = blockIdx.y * 128;

    if (AMODE == 2) {
        if (t < 128) {
            int r = row0 + t;
            i0s[t] = (r < Mr) ? I0[rowOffset + r] : 0;
        } else {
            int r = row0 + (t - 128);
            i1s[t - 128] = (r < Mr) ? I1[rowOffset + r] : 0;
        }
    }

    f32x4 acc[4][4];
#pragma unroll
    for (int i = 0; i < 4; ++i)
#pragma unroll
        for (int j = 0; j < 4; ++j) acc[i][j] = (f32x4){0.f, 0.f, 0.f, 0.f};

    for (int k0 = 0; k0 < Kd; k0 += 32) {
        __syncthreads();
        // ---- stage A: 512 slots of 8 bf16, 2 per thread ----
#pragma unroll
        for (int h = 0; h < 2; ++h) {
            int s = t + h * 256;
            int r = s >> 2, sl = s & 3;
            int row = row0 + r;
            bf16x8 val = {0, 0, 0, 0, 0, 0, 0, 0};
            if (row < Mr) {
                if (AMODE == 0) {
                    val = *(const bf16x8*)((const u16*)A0v + (size_t)row * lda + k0 + sl * 8);
                } else if (AMODE == 1) {
                    int c = k0 + sl * 8;
                    if (c < 128) {
                        const float* xp = (const float*)A0v + (size_t)row * 128 + c;
                        float4 x0 = *(const float4*)xp, x1 = *(const float4*)(xp + 4);
                        float4 s0 = *(const float4*)(sv + c), s1 = *(const float4*)(sv + c + 4);
                        float4 t0 = *(const float4*)(tv + c), t1 = *(const float4*)(tv + c + 4);
                        float4 a = make_float4(fmaf(x0.x,s0.x,t0.x), fmaf(x0.y,s0.y,t0.y),
                                               fmaf(x0.z,s0.z,t0.z), fmaf(x0.w,s0.w,t0.w));
                        float4 b = make_float4(fmaf(x1.x,s1.x,t1.x), fmaf(x1.y,s1.y,t1.y),
                                               fmaf(x1.z,s1.z,t1.z), fmaf(x1.w,s1.w,t1.w));
                        val = cvt8(a, b);
                    } else {
                        val = *(const bf16x8*)((const u16*)A1v + (size_t)row * 128 + (c - 128));
                    }
                } else if (AMODE == 3) {
                    int c = k0 + sl * 8;
                    const float* xp = (const float*)A0v + (size_t)row * 128 + c;
                    float4 x0 = *(const float4*)xp, x1 = *(const float4*)(xp + 4);
                    float4 s0 = *(const float4*)(sv + c), s1 = *(const float4*)(sv + c + 4);
                    float4 t0 = *(const float4*)(tv + c), t1 = *(const float4*)(tv + c + 4);
                    float4 a = make_float4(fmaf(x0.x,s0.x,t0.x), fmaf(x0.y,s0.y,t0.y),
                                           fmaf(x0.z,s0.z,t0.z), fmaf(x0.w,s0.w,t0.w));
                    float4 b = make_float4(fmaf(x1.x,s1.x,t1.x), fmaf(x1.y,s1.y,t1.y),
                                           fmaf(x1.z,s1.z,t1.z), fmaf(x1.w,s1.w,t1.w));
                    val = cvt8(a, b);
                } else { // AMODE 2
                    int seg = k0 >> 7;
                    int c = (k0 & 127) + sl * 8;
                    if (seg == 0) {
                        val = *(const bf16x8*)((const u16*)A0v + (size_t)i0s[r] * 128 + c);
                    } else if (seg == 1) {
                        val = *(const bf16x8*)((const u16*)A0v + (size_t)i1s[r] * 128 + c);
                    } else if (seg == 2) {
                        const float* xp = (const float*)A1v + (size_t)i0s[r] * 128 + c;
                        val = cvt8(*(const float4*)xp, *(const float4*)(xp + 4));
                    } else if (seg == 3) {
                        const float* xp = (const float*)A1v + (size_t)i1s[r] * 128 + c;
                        val = cvt8(*(const float4*)xp, *(const float4*)(xp + 4));
                    } else {
                        const float* yp = Yp + (size_t)(rowOffset + row) * 32 + sl * 8;
                        val = cvt8(*(const float4*)yp, *(const float4*)(yp + 4));
                    }
                }
            }
            *(bf16x8*)&As[r * 32 + ((sl ^ ((r >> 1) & 3)) << 3)] = val;
        }
        // ---- stage B ----
#pragma unroll
        for (int h = 0; h < 2; ++h) {
            int s = t + h * 256;
            int n = s >> 2, sl = s & 3;
            bf16x8 val = *(const bf16x8*)(Wb + (size_t)(colb + n) * Kd + k0 + sl * 8);
            *(bf16x8*)&Bs[n * 32 + ((sl ^ ((n >> 1) & 3)) << 3)] = val;
        }
        __syncthreads();
        // ---- frags + MFMA ----
        bf16x8 af[4], bfr[4];
#pragma unroll
        for (int i = 0; i < 4; ++i) {
            int r = wm * 64 + i * 16 + lb;
            af[i] = *(const bf16x8*)&As[r * 32 + ((lh ^ ((r >> 1) & 3)) << 3)];
        }
#pragma unroll
        for (int j = 0; j < 4; ++j) {
            int n = wn * 64 + j * 16 + lb;
            bfr[j] = *(const bf16x8*)&Bs[n * 32 + ((lh ^ ((n >> 1) & 3)) << 3)];
        }
#pragma unroll
        for (int i = 0; i < 4; ++i)
#pragma unroll
            for (int j = 0; j < 4; ++j)
                acc[i][j] = __builtin_amdgcn_mfma_f32_16x16x32_bf16(af[i], bfr[j], acc[i][j], 0, 0, 0);
    }

    // ---- epilogue: C/D layout col=lane&15, row=(lane>>4)*4+reg ----
#pragma unroll
    for (int i = 0; i < 4; ++i) {
#pragma unroll
        for (int j = 0; j < 4; ++j) {
            int col = colb + wn * 64 + j * 16 + lb;
#pragma unroll
            for (int r = 0; r < 4; ++r) {
                int row = row0 + wm * 64 + i * 16 + lh * 4 + r;
                if (row < Mr) {
                    size_t off = (size_t)row * Nc + col;
                    float v = acc[i][j][r];
                    if (ACCUM) v += ((const float*)Cv)[off];
                    if (ACT) v = gelu_erf(v + bias[col]);
                    if (OUTBF) ((u16*)Cv)[off] = f2b(v);
                    else       ((float*)Cv)[off] = v;
                }
            }
        }
    }
}

// logits = cl @ endW + endB ; softmax over 8 ; one wave per row
__global__ void node_head(const float* __restrict__ cl, const float* __restrict__ Wend,
                          const float* __restrict__ bend, float* __restrict__ out, int m)
{
    __shared__ float WsT[8 * 128];
    __shared__ float bs[8];
    int t = threadIdx.x;
    for (int i = t; i < 1024; i += 256) {
        int k = i >> 3, j = i & 7;
        WsT[j * 128 + k] = Wend[i];
    }
    if (t < 8) bs[t] = bend[t];
    __syncthreads();
    int gid = blockIdx.x * 256 + t;
    int wave = gid >> 6, lane = gid & 63;
    if (wave >= m) return;
    float v0 = cl[(size_t)wave * 128 + lane];
    float v1 = cl[(size_t)wave * 128 + lane + 64];
    float lg[8];
#pragma unroll
    for (int j = 0; j < 8; ++j) {
        float p = v0 * WsT[j * 128 + lane] + v1 * WsT[j * 128 + lane + 64];
#pragma unroll
        for (int o = 32; o; o >>= 1) p += __shfl_down(p, o);
        lg[j] = p;
    }
    if (lane == 0) {
        float mx = -1e30f;
#pragma unroll
        for (int j = 0; j < 8; ++j) { lg[j] += bs[j]; mx = fmaxf(mx, lg[j]); }
        float s = 0.f;
#pragma unroll
        for (int j = 0; j < 8; ++j) { lg[j] = expf(lg[j] - mx); s += lg[j]; }
        float inv = 1.f / s;
#pragma unroll
        for (int j = 0; j < 8; ++j) out[(size_t)wave * 8 + j] = lg[j] * inv;
    }
}

// e_pred = sigmoid(o2 @ elEW + b) ; one wave per row, K=256 (o2 fp32)
__global__ void edge_head(const float* __restrict__ o2, const float* __restrict__ Wend,
                          const float* __restrict__ bend, float* __restrict__ out, int m)
{
    int gid = blockIdx.x * blockDim.x + threadIdx.x;
    int wave = gid >> 6, lane = gid & 63;
    if (wave >= m) return;
    float4 wv = *(const float4*)&Wend[lane * 4];
    float4 xv = *(const float4*)&o2[(size_t)wave * 256 + lane * 4];
    float p = xv.x * wv.x + xv.y * wv.y + xv.z * wv.z + xv.w * wv.w;
#pragma unroll
    for (int o = 32; o; o >>= 1) p += __shfl_down(p, o);
    if (lane == 0) out[wave] = 1.f / (1.f + expf(-(p + bend[0])));
}

extern "C" void kernel_launch(void* const* d_in, const int* in_sizes, int n_in,
                              void* d_out, int out_size, void* d_ws, size_t ws_size,
                              hipStream_t stream)
{
    const float* X    = (const float*)d_in[0];
    const float* Y    = (const float*)d_in[1];
    const int*   EI   = (const int*)d_in[2];
    const int*   I0   = (const int*)d_in[3];
    const int*   I1   = (const int*)d_in[4];
    const float* bnG  = (const float*)d_in[5];
    const float* bnB  = (const float*)d_in[6];
    const float* Wlin = (const float*)d_in[7];
    const float* blin = (const float*)d_in[8];
    const float* tagWs= (const float*)d_in[9];
    const float* tagB = (const float*)d_in[10];
    const float* nlW0 = (const float*)d_in[11];
    const float* nlb0 = (const float*)d_in[12];
    const float* nlW1 = (const float*)d_in[13];
    const float* nlb1 = (const float*)d_in[14];
    const float* clW  = (const float*)d_in[15];
    const float* clb  = (const float*)d_in[16];
    const float* endW = (const float*)d_in[17];
    const float* endB = (const float*)d_in[18];
    const float* beG  = (const float*)d_in[19];
    const float* beB  = (const float*)d_in[20];
    const float* elW0 = (const float*)d_in[21];
    const float* elb0 = (const float*)d_in[22];
    const float* elW1 = (const float*)d_in[23];
    const float* elb1 = (const float*)d_in[24];
    const float* elEW = (const float*)d_in[25];
    const float* elEb = (const float*)d_in[26];

    const int N = NN, E = NE, P = NP;

    char* w = (char*)d_ws;
    size_t off = 0;
    auto alloc = [&](size_t bytes) -> void* {
        void* p = w + off;
        off += (bytes + 255) & ~(size_t)255;
        return p;
    };

    // --- zeroed region ---
    size_t zeroBytes = (size_t)(544 + 544 + 128 + 128) * 4 + (size_t)4 * N * 4;
    char* zr = (char*)alloc(zeroBytes);
    float* statS = (float*)zr;
    float* statQ = statS + 544;
    float* nodeS = statQ + 544;
    float* nodeQ = nodeS + 128;
    int* cnt    = (int*)(nodeQ + 128);
    int* cursor = cnt + N;
    int* cnt0   = cursor + N;
    int* cnt1   = cnt0 + N;

    int*   indptr = (int*)alloc((size_t)(N + 1) * 4);
    float* dinv   = (float*)alloc((size_t)N * 4);
    int*   csrS   = (int*)alloc((size_t)E * 4);
    float* sNode  = (float*)alloc(128 * 4);
    float* tNode  = (float*)alloc(128 * 4);
    float* sEdge  = (float*)alloc(544 * 4);
    float* tEdge  = (float*)alloc(544 * 4);
    float* b0p    = (float*)alloc(512 * 4);
    // bf16 transposed weights
    u16* Wlinb  = (u16*)alloc((size_t)128 * 128 * 2);
    u16* tagWsb = (u16*)alloc((size_t)7 * 128 * 128 * 2);
    u16* nlW0b  = (u16*)alloc((size_t)256 * 256 * 2);
    u16* nlW1b  = (u16*)alloc((size_t)128 * 256 * 2);
    u16* clWb   = (u16*)alloc((size_t)128 * 128 * 2);
    u16* elW1b  = (u16*)alloc((size_t)256 * 512 * 2);
    u16* W0pb   = (u16*)alloc((size_t)512 * 544 * 2);
    // big buffers
    u16*   hA   = (u16*)alloc((size_t)N * 128 * 2);   // h ping / aEmb
    u16*   hB   = (u16*)alloc((size_t)N * 128 * 2);   // h pong / houtb
    float* outT = (float*)alloc((size_t)N * 128 * 4); // fp32 TAG acc / chunk region

    if (ws_size < off) return;   // diagnostic: clean absmax fail instead of a fault

    u16*   aEmb  = hA;
    u16*   houtb = hB;
    float* out_nodes = (float*)d_out;
    float* out_epred = (float*)d_out + (size_t)N * 8;

    hipMemsetAsync(zr, 0, zeroBytes, stream);

    // ---- weight conversions (transposed bf16) ----
    convT<<<(128*128 + 255)/256, 256, 0, stream>>>(Wlin, Wlinb, 128, 128);
    for (int k = 0; k < 7; ++k)
        convT<<<(128*128 + 255)/256, 256, 0, stream>>>(tagWs + (size_t)k*128*128,
                                                       tagWsb + (size_t)k*128*128, 128, 128);
    convT<<<(256*256 + 255)/256, 256, 0, stream>>>(nlW0, nlW0b, 256, 256);
    convT<<<(256*128 + 255)/256, 256, 0, stream>>>(nlW1, nlW1b, 256, 128);
    convT<<<(128*128 + 255)/256, 256, 0, stream>>>(clW, clWb, 128, 128);
    convT<<<(512*256 + 255)/256, 256, 0, stream>>>(elW1, elW1b, 512, 256);

    // ---- node BN stats ----
    col_stats<0><<<1024, 256, 0, stream>>>(X, N, 7, nullptr, nullptr, nodeS, nodeQ, 0, 0);
    bn_finalize<<<1, 128, 0, stream>>>(nodeS, nodeQ, bnG, bnB, sNode, tNode, 128, (float)N, 1e-5f);

    // ---- tag linear: hA = bf16(gelu(BN(X) @ Wlin + blin)) ----
    dim3 g1((N + 127) / 128, 1);
    gemm_mfma<3, 1, 0, 1><<<g1, 256, 0, stream>>>(X, nullptr, nullptr, nullptr, nullptr, 0,
                                                  sNode, tNode, Wlinb, blin, hA, N, 128, 128, 128);

    // ---- graph prep ----
    hist_add<<<2048, 256, 0, stream>>>(EI + E, E, cnt);
    hist_add<<<1024, 256, 0, stream>>>(I0, P, cnt0);
    hist_add<<<1024, 256, 0, stream>>>(I1, P, cnt1);
    exscan1024<<<1, 1024, 0, stream>>>(cnt, indptr, N);
    make_dinv<<<(N + 255) / 256, 256, 0, stream>>>(cnt, dinv, N);
    csr_build<<<2048, 256, 0, stream>>>(EI, EI + E, E, indptr, cursor, csrS);

    // ---- TAGConv: outT(fp32) = sum_k S^k h @ Ws[k] ----
    gemm_mfma<0, 0, 0, 0><<<g1, 256, 0, stream>>>(hA, nullptr, nullptr, nullptr, nullptr, 0,
                                                  nullptr, nullptr, tagWsb, nullptr, outT, N, 128, 128, 128);
    u16* cur = hA; u16* nxt = hB;
    for (int k = 1; k <= KHOPS; ++k) {
        spmm_hop<<<(N * 64 + 255) / 256, 256, 0, stream>>>(cur, nxt, indptr, csrS, dinv);
        gemm_mfma<0, 0, 1, 0><<<g1, 256, 0, stream>>>(nxt, nullptr, nullptr, nullptr, nullptr, 0,
                                                      nullptr, nullptr, tagWsb + (size_t)k*128*128,
                                                      nullptr, outT, N, 128, 128, 128);
        u16* tmp = cur; cur = nxt; nxt = tmp;
    }
    // houtb(bf16, in hB) = gelu(outT + tagB); outT dead afterwards -> chunk region
    gelu_bias_bf<<<2048, 256, 0, stream>>>(outT, tagB, houtb, N * 128 / 4);

    // ---- node MLP: chunk buffers alias outT ----
    u16*   a256  = (u16*)outT;                                   // [NCHK,256] bf16
    float* clbuf = (float*)((char*)outT + (size_t)NCHK * 256 * 2); // [NCHK,128] f32
    for (int nb = 0; nb < N; nb += NCHK) {
        int m = (N - nb < NCHK) ? (N - nb) : NCHK;
        dim3 gA((m + 127) / 128, 2);
        gemm_mfma<1, 1, 0, 1><<<gA, 256, 0, stream>>>(X + (size_t)nb * 128, houtb + (size_t)nb * 128,
                                                      nullptr, nullptr, nullptr, 0,
                                                      sNode, tNode, nlW0b, nlb0, a256, m, 256, 256, 0);
        dim3 gB((m + 127) / 128, 1);
        gemm_mfma<0, 1, 0, 1><<<gB, 256, 0, stream>>>(a256, nullptr, nullptr, nullptr, nullptr, 0,
                                                      nullptr, nullptr, nlW1b, nlb1,
                                                      aEmb + (size_t)nb * 128, m, 256, 128, 256);
        gemm_mfma<0, 1, 0, 0><<<gB, 256, 0, stream>>>(aEmb + (size_t)nb * 128, nullptr, nullptr, nullptr, nullptr, 0,
                                                      nullptr, nullptr, clWb, clb, clbuf, m, 128, 128, 128);
        node_head<<<(m + 3) / 4, 256, 0, stream>>>(clbuf, endW, endB, out_nodes + (size_t)nb * 8, m);
    }

    // ---- edge BN stats (count-weighted, exact) ----
    col_stats<1><<<1024, 256, 0, stream>>>(aEmb, N, 7, cnt0, cnt1, statS, statQ, 0, 128);
    col_stats<0><<<1024, 256, 0, stream>>>(X,    N, 7, cnt0, cnt1, statS, statQ, 256, 384);
    col_stats<0><<<1024, 256, 0, stream>>>(Y,    P, 5, nullptr, nullptr, statS, statQ, 512, 0);
    bn_finalize<<<3, 256, 0, stream>>>(statS, statQ, beG, beB, sEdge, tEdge, 544, (float)P, 1.0f);
    fold_wT<<<(512*544 + 255)/256, 256, 0, stream>>>(elW0, sEdge, W0pb);
    fold_b<<<2, 256, 0, stream>>>(elW0, elb0, tEdge, b0p);

    // ---- edge MLP: chunk buffers alias outT ----
    u16*   o1 = (u16*)outT;                                        // [NCHK,512] bf16
    float* o2 = (float*)((char*)outT + (size_t)NCHK * 512 * 2);    // [NCHK,256] f32
    for (int pb = 0; pb < P; pb += NCHK) {
        int m = (P - pb < NCHK) ? (P - pb) : NCHK;
        dim3 gA((m + 127) / 128, 4);
        gemm_mfma<2, 1, 0, 1><<<gA, 256, 0, stream>>>(aEmb, X, Y, I0, I1, pb,
                                                      nullptr, nullptr, W0pb, b0p, o1, m, 544, 512, 0);
        dim3 gB((m + 127) / 128, 2);
        gemm_mfma<0, 1, 0, 0><<<gB, 256, 0, stream>>>(o1, nullptr, nullptr, nullptr, nullptr, 0,
                                                      nullptr, nullptr, elW1b, elb1, o2, m, 512, 256, 512);
        edge_head<<<(m + 3) / 4, 256, 0, stream>>>(o2, elEW, elEb, out_epred + pb, m);
    }
}

// Round 6
// 2889.330 us; speedup vs baseline: 3.7918x; 1.3375x over previous
//
#include <hip/hip_runtime.h>
#include <math.h>

#define NN 100000
#define NE 1600000
#define NP 500000
#define KHOPS 6
#define ECHK 50000          // edge chunk rows (hB+outT region, 76.8 MB)
#define NB_SCAN ((NN + 1023) / 1024)

typedef unsigned short u16;
typedef short bf16x8 __attribute__((ext_vector_type(8)));
typedef float f32x4 __attribute__((ext_vector_type(4)));

__device__ __forceinline__ float gelu_erf(float x) {
    return 0.5f * x * (1.0f + erff(x * 0.70710678118654752f));
}
__device__ __forceinline__ float b2f(u16 u) {
    return __uint_as_float(((unsigned int)u) << 16);
}
__device__ __forceinline__ u16 f2b(float f) {
    unsigned int x = __float_as_uint(f);
    return (u16)((x + 0x7FFFu + ((x >> 16) & 1u)) >> 16);
}
__device__ __forceinline__ bf16x8 cvt8(float4 a, float4 b) {
    bf16x8 v;
    v[0]=(short)f2b(a.x); v[1]=(short)f2b(a.y); v[2]=(short)f2b(a.z); v[3]=(short)f2b(a.w);
    v[4]=(short)f2b(b.x); v[5]=(short)f2b(b.y); v[6]=(short)f2b(b.z); v[7]=(short)f2b(b.w);
    return v;
}

// ---------------- column statistics (optionally weighted by up to 2 int count vectors)
template<int BF>
__global__ void col_stats(const void* __restrict__ Matv, int rows, int lc,
                          const int* __restrict__ w0, const int* __restrict__ w1,
                          float* __restrict__ sums, float* __restrict__ sumsq,
                          int base0, int base1)
{
    __shared__ float red[256];
    const int t = threadIdx.x;
    const int C = 1 << lc;
    const long total = (long)rows << lc;
    const long stride = (long)gridDim.x * 256;
    float s0 = 0.f, q0 = 0.f, s1 = 0.f, q1 = 0.f;
    for (long idx = (long)blockIdx.x * 256 + t; idx < total; idx += stride) {
        int r = (int)(idx >> lc);
        float v = BF ? b2f(((const u16*)Matv)[idx]) : ((const float*)Matv)[idx];
        float f0 = w0 ? (float)w0[r] : 1.0f;
        s0 += f0 * v;
        q0 += f0 * v * v;
        if (w1) {
            float f1 = (float)w1[r];
            s1 += f1 * v;
            q1 += f1 * v * v;
        }
    }
    red[t] = s0; __syncthreads();
    if (t < C) { float x = 0.f; for (int k = t; k < 256; k += C) x += red[k]; atomicAdd(&sums[base0 + t], x); }
    __syncthreads();
    red[t] = q0; __syncthreads();
    if (t < C) { float x = 0.f; for (int k = t; k < 256; k += C) x += red[k]; atomicAdd(&sumsq[base0 + t], x); }
    __syncthreads();
    if (w1) {
        red[t] = s1; __syncthreads();
        if (t < C) { float x = 0.f; for (int k = t; k < 256; k += C) x += red[k]; atomicAdd(&sums[base1 + t], x); }
        __syncthreads();
        red[t] = q1; __syncthreads();
        if (t < C) { float x = 0.f; for (int k = t; k < 256; k += C) x += red[k]; atomicAdd(&sumsq[base1 + t], x); }
    }
}

__global__ void bn_finalize(const float* __restrict__ sums, const float* __restrict__ sumsq,
                            const float* __restrict__ g, const float* __restrict__ b,
                            float* __restrict__ s, float* __restrict__ t,
                            int C, float count, float eps)
{
    int c = blockIdx.x * blockDim.x + threadIdx.x;
    if (c < C) {
        float mu = sums[c] / count;
        float var = sumsq[c] / count - mu * mu;
        float sc = g[c] * rsqrtf(var + eps);
        s[c] = sc;
        t[c] = b[c] - mu * sc;
    }
}

__global__ void gelu_bias_bf(const float* __restrict__ x, const float* __restrict__ bias,
                             u16* __restrict__ out, int n4)
{
    int stride = gridDim.x * blockDim.x;
    for (int i = blockIdx.x * blockDim.x + threadIdx.x; i < n4; i += stride) {
        int c4 = (i & 31) * 4;
        float4 v = ((const float4*)x)[i];
        ushort4 o;
        o.x = f2b(gelu_erf(v.x + bias[c4 + 0]));
        o.y = f2b(gelu_erf(v.y + bias[c4 + 1]));
        o.z = f2b(gelu_erf(v.z + bias[c4 + 2]));
        o.w = f2b(gelu_erf(v.w + bias[c4 + 3]));
        ((ushort4*)out)[i] = o;
    }
}

__global__ void hist_add(const int* __restrict__ idx, int n, int* __restrict__ cnt)
{
    int stride = gridDim.x * blockDim.x;
    for (int i = blockIdx.x * blockDim.x + threadIdx.x; i < n; i += stride)
        atomicAdd(&cnt[idx[i]], 1);
}

// both pair-index histograms in one pass
__global__ void hist_add2(const int* __restrict__ i0, const int* __restrict__ i1, int n,
                          int* __restrict__ c0, int* __restrict__ c1)
{
    int stride = gridDim.x * blockDim.x;
    for (int i = blockIdx.x * blockDim.x + threadIdx.x; i < n; i += stride) {
        atomicAdd(&c0[i0[i]], 1);
        atomicAdd(&c1[i1[i]], 1);
    }
}

// ---- 3-phase scan: per-block exclusive scan + partials
__global__ void scan1(const int* __restrict__ cnt, int* __restrict__ ex,
                      int* __restrict__ part, int n)
{
    __shared__ int buf[1024];
    int b = blockIdx.x, t = threadIdx.x;
    int i = b * 1024 + t;
    int v = (i < n) ? cnt[i] : 0;
    buf[t] = v;
    __syncthreads();
    int incl = v;
    for (int o = 1; o < 1024; o <<= 1) {
        int tmp = (t >= o) ? buf[t - o] : 0;
        __syncthreads();
        incl += tmp;
        buf[t] = incl;
        __syncthreads();
    }
    if (i < n) ex[i] = incl - v;
    if (t == 1023) part[b] = incl;
}

__global__ void scan2(int* __restrict__ part, int nb)
{
    __shared__ int s[256];
    int t = threadIdx.x;
    if (t < nb) s[t] = part[t];
    __syncthreads();
    if (t == 0) {
        int run = 0;
        for (int b = 0; b < nb; ++b) { int x = s[b]; part[b] = run; run += x; }
        part[nb] = run;
    }
}

// offsets + indptr[n] + dinv fused
__global__ void scan3(int* __restrict__ indptr, const int* __restrict__ part,
                      const int* __restrict__ cnt, float* __restrict__ dinv, int n)
{
    int b = blockIdx.x, t = threadIdx.x;
    int i = b * 1024 + t;
    if (i < n) {
        indptr[i] += part[b];
        int c = cnt[i];
        dinv[i] = (c > 0) ? rsqrtf((float)c) : 0.f;
    }
    if (b == 0 && t == 0) indptr[n] = part[NB_SCAN];
}

__global__ void csr_build(const int* __restrict__ src, const int* __restrict__ dst, int n,
                          const int* __restrict__ indptr, int* __restrict__ cursor,
                          int* __restrict__ csrS)
{
    int stride = gridDim.x * blockDim.x;
    for (int e = blockIdx.x * blockDim.x + threadIdx.x; e < n; e += stride) {
        int s = src[e], d = dst[e];
        int pos = indptr[d] + atomicAdd(&cursor[d], 1);
        csrS[pos] = s;
    }
}

// hout[n, 2l..2l+1] via ushort2; 2-edge unroll
__global__ void spmm_hop(const u16* __restrict__ hin, u16* __restrict__ hout,
                         const int* __restrict__ indptr, const int* __restrict__ csrS,
                         const float* __restrict__ dinv)
{
    int gid = blockIdx.x * blockDim.x + threadIdx.x;
    int node = gid >> 6;
    int lane = gid & 63;
    if (node >= NN) return;
    float dn = dinv[node];
    int beg = indptr[node], end = indptr[node + 1];
    float a0 = 0.f, a1 = 0.f;
    int e = beg;
    for (; e + 1 < end; e += 2) {
        int s0 = csrS[e], s1 = csrS[e + 1];
        float w0 = dn * dinv[s0], w1 = dn * dinv[s1];
        ushort2 p0 = *(const ushort2*)(hin + (size_t)s0 * 128 + lane * 2);
        ushort2 p1 = *(const ushort2*)(hin + (size_t)s1 * 128 + lane * 2);
        a0 = fmaf(w0, b2f(p0.x), a0);
        a1 = fmaf(w0, b2f(p0.y), a1);
        a0 = fmaf(w1, b2f(p1.x), a0);
        a1 = fmaf(w1, b2f(p1.y), a1);
    }
    if (e < end) {
        int s0 = csrS[e];
        float w0 = dn * dinv[s0];
        ushort2 p0 = *(const ushort2*)(hin + (size_t)s0 * 128 + lane * 2);
        a0 = fmaf(w0, b2f(p0.x), a0);
        a1 = fmaf(w0, b2f(p0.y), a1);
    }
    ushort2 o;
    o.x = f2b(a0); o.y = f2b(a1);
    *(ushort2*)(hout + (size_t)node * 128 + lane * 2) = o;
}

// batched transpose+convert: out[m][n][k] = bf16(in[m][k][n]), B mats of K x Nc
__global__ void convTB(const float* __restrict__ in, u16* __restrict__ out,
                       int K, int Nc, int B)
{
    int per = K * Nc;
    int i = blockIdx.x * blockDim.x + threadIdx.x;
    if (i < per * B) {
        int m = i / per, r = i - m * per;
        int n = r / K, k = r - n * K;
        out[i] = f2b(in[(size_t)m * per + (size_t)k * Nc + n]);
    }
}

// W0pb[n*544+k] = bf16(s[k]*elW0[k*512+n])
__global__ void fold_wT(const float* __restrict__ W0, const float* __restrict__ s,
                        u16* __restrict__ out)
{
    int i = blockIdx.x * blockDim.x + threadIdx.x;
    if (i < 512 * 544) {
        int n = i / 544, k = i - n * 544;
        out[i] = f2b(s[k] * W0[(size_t)k * 512 + n]);
    }
}

__global__ void fold_b(const float* __restrict__ W0, const float* __restrict__ b0,
                       const float* __restrict__ tv, float* __restrict__ bp)
{
    int j = blockIdx.x * blockDim.x + threadIdx.x;
    if (j < 512) {
        float s = b0[j];
        for (int k = 0; k < 544; ++k) s = fmaf(tv[k], W0[k * 512 + j], s);
        bp[j] = s;
    }
}

// ------------- MFMA bf16 GEMM: tile 128x128, BK=32, 4 waves (2x2), 64x64/wave
// B pre-transposed bf16: Wb[n][k]. AMODE/ACT/ACCUM/OUTBF as before.
template<int AMODE, int ACT, int ACCUM, int OUTBF>
__launch_bounds__(256, 2)
__global__ void gemm_mfma(const void* __restrict__ A0v, const void* __restrict__ A1v,
                          const float* __restrict__ Yp,
                          const int* __restrict__ I0, const int* __restrict__ I1,
                          int rowOffset,
                          const float* __restrict__ sv, const float* __restrict__ tv,
                          const u16* __restrict__ Wb, const float* __restrict__ bias,
                          void* __restrict__ Cv, int Mr, int Kd, int Nc, int lda)
{
    __shared__ __align__(16) u16 As[128 * 32];
    __shared__ __align__(16) u16 Bs[128 * 32];
    __shared__ int i0s[128], i1s[128];

    const int t = threadIdx.x;
    const int lane = t & 63;
    const int wid = t >> 6;
    const int wm = wid >> 1, wn = wid & 1;
    const int lb = lane & 15, lh = lane >> 4;
    const int row0 = blockIdx.x * 128;
    const int colb = blockIdx.y * 128;

    if (AMODE == 2) {
        if (t < 128) {
            int r = row0 + t;
            i0s[t] = (r < Mr) ? I0[rowOffset + r] : 0;
        } else {
            int r = row0 + (t - 128);
            i1s[t - 128] = (r < Mr) ? I1[rowOffset + r] : 0;
        }
    }

    f32x4 acc[4][4];
#pragma unroll
    for (int i = 0; i < 4; ++i)
#pragma unroll
        for (int j = 0; j < 4; ++j) acc[i][j] = (f32x4){0.f, 0.f, 0.f, 0.f};

    for (int k0 = 0; k0 < Kd; k0 += 32) {
        __syncthreads();
#pragma unroll
        for (int h = 0; h < 2; ++h) {
            int s = t + h * 256;
            int r = s >> 2, sl = s & 3;
            int row = row0 + r;
            bf16x8 val = {0, 0, 0, 0, 0, 0, 0, 0};
            if (row < Mr) {
                if (AMODE == 0) {
                    val = *(const bf16x8*)((const u16*)A0v + (size_t)row * lda + k0 + sl * 8);
                } else if (AMODE == 1) {
                    int c = k0 + sl * 8;
                    if (c < 128) {
                        const float* xp = (const float*)A0v + (size_t)row * 128 + c;
                        float4 x0 = *(const float4*)xp, x1 = *(const float4*)(xp + 4);
                        float4 s0 = *(const float4*)(sv + c), s1 = *(const float4*)(sv + c + 4);
                        float4 t0 = *(const float4*)(tv + c), t1 = *(const float4*)(tv + c + 4);
                        float4 a = make_float4(fmaf(x0.x,s0.x,t0.x), fmaf(x0.y,s0.y,t0.y),
                                               fmaf(x0.z,s0.z,t0.z), fmaf(x0.w,s0.w,t0.w));
                        float4 b = make_float4(fmaf(x1.x,s1.x,t1.x), fmaf(x1.y,s1.y,t1.y),
                                               fmaf(x1.z,s1.z,t1.z), fmaf(x1.w,s1.w,t1.w));
                        val = cvt8(a, b);
                    } else {
                        val = *(const bf16x8*)((const u16*)A1v + (size_t)row * 128 + (c - 128));
                    }
                } else if (AMODE == 3) {
                    int c = k0 + sl * 8;
                    const float* xp = (const float*)A0v + (size_t)row * 128 + c;
                    float4 x0 = *(const float4*)xp, x1 = *(const float4*)(xp + 4);
                    float4 s0 = *(const float4*)(sv + c), s1 = *(const float4*)(sv + c + 4);
                    float4 t0 = *(const float4*)(tv + c), t1 = *(const float4*)(tv + c + 4);
                    float4 a = make_float4(fmaf(x0.x,s0.x,t0.x), fmaf(x0.y,s0.y,t0.y),
                                           fmaf(x0.z,s0.z,t0.z), fmaf(x0.w,s0.w,t0.w));
                    float4 b = make_float4(fmaf(x1.x,s1.x,t1.x), fmaf(x1.y,s1.y,t1.y),
                                           fmaf(x1.z,s1.z,t1.z), fmaf(x1.w,s1.w,t1.w));
                    val = cvt8(a, b);
                } else { // AMODE 2
                    int seg = k0 >> 7;
                    int c = (k0 & 127) + sl * 8;
                    if (seg == 0) {
                        val = *(const bf16x8*)((const u16*)A0v + (size_t)i0s[r] * 128 + c);
                    } else if (seg == 1) {
                        val = *(const bf16x8*)((const u16*)A0v + (size_t)i1s[r] * 128 + c);
                    } else if (seg == 2) {
                        const float* xp = (const float*)A1v + (size_t)i0s[r] * 128 + c;
                        val = cvt8(*(const float4*)xp, *(const float4*)(xp + 4));
                    } else if (seg == 3) {
                        const float* xp = (const float*)A1v + (size_t)i1s[r] * 128 + c;
                        val = cvt8(*(const float4*)xp, *(const float4*)(xp + 4));
                    } else {
                        const float* yp = Yp + (size_t)(rowOffset + row) * 32 + sl * 8;
                        val = cvt8(*(const float4*)yp, *(const float4*)(yp + 4));
                    }
                }
            }
            *(bf16x8*)&As[r * 32 + ((sl ^ ((r >> 1) & 3)) << 3)] = val;
        }
#pragma unroll
        for (int h = 0; h < 2; ++h) {
            int s = t + h * 256;
            int n = s >> 2, sl = s & 3;
            bf16x8 val = *(const bf16x8*)(Wb + (size_t)(colb + n) * Kd + k0 + sl * 8);
            *(bf16x8*)&Bs[n * 32 + ((sl ^ ((n >> 1) & 3)) << 3)] = val;
        }
        __syncthreads();
        bf16x8 af[4], bfr[4];
#pragma unroll
        for (int i = 0; i < 4; ++i) {
            int r = wm * 64 + i * 16 + lb;
            af[i] = *(const bf16x8*)&As[r * 32 + ((lh ^ ((r >> 1) & 3)) << 3)];
        }
#pragma unroll
        for (int j = 0; j < 4; ++j) {
            int n = wn * 64 + j * 16 + lb;
            bfr[j] = *(const bf16x8*)&Bs[n * 32 + ((lh ^ ((n >> 1) & 3)) << 3)];
        }
#pragma unroll
        for (int i = 0; i < 4; ++i)
#pragma unroll
            for (int j = 0; j < 4; ++j)
                acc[i][j] = __builtin_amdgcn_mfma_f32_16x16x32_bf16(af[i], bfr[j], acc[i][j], 0, 0, 0);
    }

#pragma unroll
    for (int i = 0; i < 4; ++i) {
#pragma unroll
        for (int j = 0; j < 4; ++j) {
            int col = colb + wn * 64 + j * 16 + lb;
#pragma unroll
            for (int r = 0; r < 4; ++r) {
                int row = row0 + wm * 64 + i * 16 + lh * 4 + r;
                if (row < Mr) {
                    size_t off = (size_t)row * Nc + col;
                    float v = acc[i][j][r];
                    if (ACCUM) v += ((const float*)Cv)[off];
                    if (ACT) v = gelu_erf(v + bias[col]);
                    if (OUTBF) ((u16*)Cv)[off] = f2b(v);
                    else       ((float*)Cv)[off] = v;
                }
            }
        }
    }
}

// logits = cl @ endW + endB ; softmax over 8 ; one wave per row
__global__ void node_head(const float* __restrict__ cl, const float* __restrict__ Wend,
                          const float* __restrict__ bend, float* __restrict__ out, int m)
{
    __shared__ float WsT[8 * 128];
    __shared__ float bs[8];
    int t = threadIdx.x;
    for (int i = t; i < 1024; i += 256) {
        int k = i >> 3, j = i & 7;
        WsT[j * 128 + k] = Wend[i];
    }
    if (t < 8) bs[t] = bend[t];
    __syncthreads();
    int gid = blockIdx.x * 256 + t;
    int wave = gid >> 6, lane = gid & 63;
    if (wave >= m) return;
    float v0 = cl[(size_t)wave * 128 + lane];
    float v1 = cl[(size_t)wave * 128 + lane + 64];
    float lg[8];
#pragma unroll
    for (int j = 0; j < 8; ++j) {
        float p = v0 * WsT[j * 128 + lane] + v1 * WsT[j * 128 + lane + 64];
#pragma unroll
        for (int o = 32; o; o >>= 1) p += __shfl_down(p, o);
        lg[j] = p;
    }
    if (lane == 0) {
        float mx = -1e30f;
#pragma unroll
        for (int j = 0; j < 8; ++j) { lg[j] += bs[j]; mx = fmaxf(mx, lg[j]); }
        float s = 0.f;
#pragma unroll
        for (int j = 0; j < 8; ++j) { lg[j] = expf(lg[j] - mx); s += lg[j]; }
        float inv = 1.f / s;
#pragma unroll
        for (int j = 0; j < 8; ++j) out[(size_t)wave * 8 + j] = lg[j] * inv;
    }
}

// e_pred = sigmoid(o2(bf16) @ elEW + b) ; one wave per row, K=256
__global__ void edge_head(const u16* __restrict__ o2, const float* __restrict__ Wend,
                          const float* __restrict__ bend, float* __restrict__ out, int m)
{
    int gid = blockIdx.x * blockDim.x + threadIdx.x;
    int wave = gid >> 6, lane = gid & 63;
    if (wave >= m) return;
    float4 wv = *(const float4*)&Wend[lane * 4];
    ushort4 xv = *(const ushort4*)&o2[(size_t)wave * 256 + lane * 4];
    float p = b2f(xv.x) * wv.x + b2f(xv.y) * wv.y + b2f(xv.z) * wv.z + b2f(xv.w) * wv.w;
#pragma unroll
    for (int o = 32; o; o >>= 1) p += __shfl_down(p, o);
    if (lane == 0) out[wave] = 1.f / (1.f + expf(-(p + bend[0])));
}

extern "C" void kernel_launch(void* const* d_in, const int* in_sizes, int n_in,
                              void* d_out, int out_size, void* d_ws, size_t ws_size,
                              hipStream_t stream)
{
    const float* X    = (const float*)d_in[0];
    const float* Y    = (const float*)d_in[1];
    const int*   EI   = (const int*)d_in[2];
    const int*   I0   = (const int*)d_in[3];
    const int*   I1   = (const int*)d_in[4];
    const float* bnG  = (const float*)d_in[5];
    const float* bnB  = (const float*)d_in[6];
    const float* Wlin = (const float*)d_in[7];
    const float* blin = (const float*)d_in[8];
    const float* tagWs= (const float*)d_in[9];
    const float* tagB = (const float*)d_in[10];
    const float* nlW0 = (const float*)d_in[11];
    const float* nlb0 = (const float*)d_in[12];
    const float* nlW1 = (const float*)d_in[13];
    const float* nlb1 = (const float*)d_in[14];
    const float* clW  = (const float*)d_in[15];
    const float* clb  = (const float*)d_in[16];
    const float* endW = (const float*)d_in[17];
    const float* endB = (const float*)d_in[18];
    const float* beG  = (const float*)d_in[19];
    const float* beB  = (const float*)d_in[20];
    const float* elW0 = (const float*)d_in[21];
    const float* elb0 = (const float*)d_in[22];
    const float* elW1 = (const float*)d_in[23];
    const float* elb1 = (const float*)d_in[24];
    const float* elEW = (const float*)d_in[25];
    const float* elEb = (const float*)d_in[26];

    const int N = NN, E = NE, P = NP;

    char* w = (char*)d_ws;
    size_t off = 0;
    auto alloc = [&](size_t bytes) -> void* {
        void* p = w + off;
        off += (bytes + 255) & ~(size_t)255;
        return p;
    };

    // --- zeroed region ---
    size_t zeroBytes = (size_t)(544 + 544 + 128 + 128) * 4 + (size_t)4 * N * 4;
    char* zr = (char*)alloc(zeroBytes);
    float* statS = (float*)zr;
    float* statQ = statS + 544;
    float* nodeS = statQ + 544;
    float* nodeQ = nodeS + 128;
    int* cnt    = (int*)(nodeQ + 128);
    int* cursor = cnt + N;
    int* cnt0   = cursor + N;
    int* cnt1   = cnt0 + N;

    int*   indptr = (int*)alloc((size_t)(N + 1) * 4);
    int*   part   = (int*)alloc((size_t)(NB_SCAN + 1) * 4);
    float* dinv   = (float*)alloc((size_t)N * 4);
    int*   csrS   = (int*)alloc((size_t)E * 4);
    float* sNode  = (float*)alloc(128 * 4);
    float* tNode  = (float*)alloc(128 * 4);
    float* sEdge  = (float*)alloc(544 * 4);
    float* tEdge  = (float*)alloc(544 * 4);
    float* b0p    = (float*)alloc(512 * 4);
    u16* Wlinb  = (u16*)alloc((size_t)128 * 128 * 2);
    u16* tagWsb = (u16*)alloc((size_t)7 * 128 * 128 * 2);
    u16* nlW0b  = (u16*)alloc((size_t)256 * 256 * 2);
    u16* nlW1b  = (u16*)alloc((size_t)128 * 256 * 2);
    u16* clWb   = (u16*)alloc((size_t)128 * 128 * 2);
    u16* elW1b  = (u16*)alloc((size_t)256 * 512 * 2);
    u16* W0pb   = (u16*)alloc((size_t)512 * 544 * 2);
    // big buffers: hA | hB | outT contiguous
    u16*   hA   = (u16*)alloc((size_t)N * 128 * 2);   // h ping / aEmb
    u16*   hB   = (u16*)alloc((size_t)N * 128 * 2);   // h pong / houtb / edge chunk lo
    float* outT = (float*)alloc((size_t)N * 128 * 4); // TAG acc / a256+clbuf / edge chunk hi

    if (ws_size < off) return;   // diagnostic: clean absmax fail instead of a fault

    u16*   aEmb  = hA;
    u16*   houtb = hB;
    float* out_nodes = (float*)d_out;
    float* out_epred = (float*)d_out + (size_t)N * 8;

    hipMemsetAsync(zr, 0, zeroBytes, stream);

    // ---- weight conversions (transposed bf16) ----
    convTB<<<(128*128 + 255)/256, 256, 0, stream>>>(Wlin, Wlinb, 128, 128, 1);
    convTB<<<(7*128*128 + 255)/256, 256, 0, stream>>>(tagWs, tagWsb, 128, 128, 7);
    convTB<<<(256*256 + 255)/256, 256, 0, stream>>>(nlW0, nlW0b, 256, 256, 1);
    convTB<<<(256*128 + 255)/256, 256, 0, stream>>>(nlW1, nlW1b, 256, 128, 1);
    convTB<<<(128*128 + 255)/256, 256, 0, stream>>>(clW, clWb, 128, 128, 1);
    convTB<<<(512*256 + 255)/256, 256, 0, stream>>>(elW1, elW1b, 512, 256, 1);

    // ---- node BN stats ----
    col_stats<0><<<1024, 256, 0, stream>>>(X, N, 7, nullptr, nullptr, nodeS, nodeQ, 0, 0);
    bn_finalize<<<1, 128, 0, stream>>>(nodeS, nodeQ, bnG, bnB, sNode, tNode, 128, (float)N, 1e-5f);

    // ---- tag linear: hA = bf16(gelu(BN(X) @ Wlin + blin)) ----
    dim3 g1((N + 127) / 128, 1);
    gemm_mfma<3, 1, 0, 1><<<g1, 256, 0, stream>>>(X, nullptr, nullptr, nullptr, nullptr, 0,
                                                  sNode, tNode, Wlinb, blin, hA, N, 128, 128, 128);

    // ---- graph prep ----
    hist_add<<<2048, 256, 0, stream>>>(EI + E, E, cnt);
    hist_add2<<<1024, 256, 0, stream>>>(I0, I1, P, cnt0, cnt1);
    scan1<<<NB_SCAN, 1024, 0, stream>>>(cnt, indptr, part, N);
    scan2<<<1, 256, 0, stream>>>(part, NB_SCAN);
    scan3<<<NB_SCAN, 1024, 0, stream>>>(indptr, part, cnt, dinv, N);
    csr_build<<<2048, 256, 0, stream>>>(EI, EI + E, E, indptr, cursor, csrS);

    // ---- TAGConv ----
    gemm_mfma<0, 0, 0, 0><<<g1, 256, 0, stream>>>(hA, nullptr, nullptr, nullptr, nullptr, 0,
                                                  nullptr, nullptr, tagWsb, nullptr, outT, N, 128, 128, 128);
    u16* cur = hA; u16* nxt = hB;
    for (int k = 1; k <= KHOPS; ++k) {
        spmm_hop<<<(N * 64 + 255) / 256, 256, 0, stream>>>(cur, nxt, indptr, csrS, dinv);
        gemm_mfma<0, 0, 1, 0><<<g1, 256, 0, stream>>>(nxt, nullptr, nullptr, nullptr, nullptr, 0,
                                                      nullptr, nullptr, tagWsb + (size_t)k*128*128,
                                                      nullptr, outT, N, 128, 128, 128);
        u16* tmp = cur; cur = nxt; nxt = tmp;
    }
    // houtb(hB) = bf16(gelu(outT + tagB)); hA (last hk) + outT dead after
    gelu_bias_bf<<<2048, 256, 0, stream>>>(outT, tagB, houtb, N * 128 / 4);

    // ---- node MLP, un-chunked; a256/clbuf alias outT ----
    u16*   a256  = (u16*)outT;     // [N,256] bf16 = 51.2 MB (exactly outT)
    float* clbuf = outT;           // [N,128] f32 reuses outT after a256 dies
    {
        dim3 gA((N + 127) / 128, 2);
        gemm_mfma<1, 1, 0, 1><<<gA, 256, 0, stream>>>(X, houtb, nullptr, nullptr, nullptr, 0,
                                                      sNode, tNode, nlW0b, nlb0, a256, N, 256, 256, 0);
        dim3 gB((N + 127) / 128, 1);
        gemm_mfma<0, 1, 0, 1><<<gB, 256, 0, stream>>>(a256, nullptr, nullptr, nullptr, nullptr, 0,
                                                      nullptr, nullptr, nlW1b, nlb1, aEmb, N, 256, 128, 256);
        gemm_mfma<0, 1, 0, 0><<<gB, 256, 0, stream>>>(aEmb, nullptr, nullptr, nullptr, nullptr, 0,
                                                      nullptr, nullptr, clWb, clb, clbuf, N, 128, 128, 128);
        node_head<<<(N + 3) / 4, 256, 0, stream>>>(clbuf, endW, endB, out_nodes, N);
    }

    // ---- edge BN stats (count-weighted, exact) ----
    col_stats<1><<<1024, 256, 0, stream>>>(aEmb, N, 7, cnt0, cnt1, statS, statQ, 0, 128);
    col_stats<0><<<1024, 256, 0, stream>>>(X,    N, 7, cnt0, cnt1, statS, statQ, 256, 384);
    col_stats<0><<<1024, 256, 0, stream>>>(Y,    P, 5, nullptr, nullptr, statS, statQ, 512, 0);
    bn_finalize<<<3, 256, 0, stream>>>(statS, statQ, beG, beB, sEdge, tEdge, 544, (float)P, 1.0f);
    fold_wT<<<(512*544 + 255)/256, 256, 0, stream>>>(elW0, sEdge, W0pb);
    fold_b<<<2, 256, 0, stream>>>(elW0, elb0, tEdge, b0p);

    // ---- edge MLP: chunk region = hB..outT end (76.8 MB), houtb/clbuf dead ----
    u16* o1 = hB;                               // [ECHK,512] bf16 = 51.2 MB
    u16* o2 = hB + (size_t)ECHK * 512;          // [ECHK,256] bf16 = 25.6 MB
    for (int pb = 0; pb < P; pb += ECHK) {
        int m = (P - pb < ECHK) ? (P - pb) : ECHK;
        dim3 gA((m + 127) / 128, 4);
        gemm_mfma<2, 1, 0, 1><<<gA, 256, 0, stream>>>(aEmb, X, Y, I0, I1, pb,
                                                      nullptr, nullptr, W0pb, b0p, o1, m, 544, 512, 0);
        dim3 gB((m + 127) / 128, 2);
        gemm_mfma<0, 1, 0, 1><<<gB, 256, 0, stream>>>(o1, nullptr, nullptr, nullptr, nullptr, 0,
                                                      nullptr, nullptr, elW1b, elb1, o2, m, 512, 256, 512);
        edge_head<<<(m + 3) / 4, 256, 0, stream>>>(o2, elEW, elEb, out_epred + pb, m);
    }
}

// Round 7
// 2569.813 us; speedup vs baseline: 4.2632x; 1.1243x over previous
//
#include <hip/hip_runtime.h>
#include <math.h>

#define NN 100000
#define NE 1600000
#define NP 500000
#define KHOPS 6
#define ECHK 75000          // edge chunk rows; o1 [ECHK,512] bf16 = 76.8 MB = hB+outT
#define NB_SCAN ((NN + 1023) / 1024)

typedef unsigned short u16;
typedef short bf16x8 __attribute__((ext_vector_type(8)));
typedef float f32x4 __attribute__((ext_vector_type(4)));

__device__ __forceinline__ float gelu_erf(float x) {
    return 0.5f * x * (1.0f + erff(x * 0.70710678118654752f));
}
__device__ __forceinline__ float b2f(u16 u) {
    return __uint_as_float(((unsigned int)u) << 16);
}
__device__ __forceinline__ u16 f2b(float f) {
    unsigned int x = __float_as_uint(f);
    return (u16)((x + 0x7FFFu + ((x >> 16) & 1u)) >> 16);
}
__device__ __forceinline__ bf16x8 cvt8(float4 a, float4 b) {
    bf16x8 v;
    v[0]=(short)f2b(a.x); v[1]=(short)f2b(a.y); v[2]=(short)f2b(a.z); v[3]=(short)f2b(a.w);
    v[4]=(short)f2b(b.x); v[5]=(short)f2b(b.y); v[6]=(short)f2b(b.z); v[7]=(short)f2b(b.w);
    return v;
}

// ---------------- column statistics (optionally weighted by up to 2 int count vectors)
template<int BF>
__global__ void col_stats(const void* __restrict__ Matv, int rows, int lc,
                          const int* __restrict__ w0, const int* __restrict__ w1,
                          float* __restrict__ sums, float* __restrict__ sumsq,
                          int base0, int base1)
{
    __shared__ float red[256];
    const int t = threadIdx.x;
    const int C = 1 << lc;
    const long total = (long)rows << lc;
    const long stride = (long)gridDim.x * 256;
    float s0 = 0.f, q0 = 0.f, s1 = 0.f, q1 = 0.f;
    for (long idx = (long)blockIdx.x * 256 + t; idx < total; idx += stride) {
        int r = (int)(idx >> lc);
        float v = BF ? b2f(((const u16*)Matv)[idx]) : ((const float*)Matv)[idx];
        float f0 = w0 ? (float)w0[r] : 1.0f;
        s0 += f0 * v;
        q0 += f0 * v * v;
        if (w1) {
            float f1 = (float)w1[r];
            s1 += f1 * v;
            q1 += f1 * v * v;
        }
    }
    red[t] = s0; __syncthreads();
    if (t < C) { float x = 0.f; for (int k = t; k < 256; k += C) x += red[k]; atomicAdd(&sums[base0 + t], x); }
    __syncthreads();
    red[t] = q0; __syncthreads();
    if (t < C) { float x = 0.f; for (int k = t; k < 256; k += C) x += red[k]; atomicAdd(&sumsq[base0 + t], x); }
    __syncthreads();
    if (w1) {
        red[t] = s1; __syncthreads();
        if (t < C) { float x = 0.f; for (int k = t; k < 256; k += C) x += red[k]; atomicAdd(&sums[base1 + t], x); }
        __syncthreads();
        red[t] = q1; __syncthreads();
        if (t < C) { float x = 0.f; for (int k = t; k < 256; k += C) x += red[k]; atomicAdd(&sumsq[base1 + t], x); }
    }
}

__global__ void bn_finalize(const float* __restrict__ sums, const float* __restrict__ sumsq,
                            const float* __restrict__ g, const float* __restrict__ b,
                            float* __restrict__ s, float* __restrict__ t,
                            int C, float count, float eps)
{
    int c = blockIdx.x * blockDim.x + threadIdx.x;
    if (c < C) {
        float mu = sums[c] / count;
        float var = sumsq[c] / count - mu * mu;
        float sc = g[c] * rsqrtf(var + eps);
        s[c] = sc;
        t[c] = b[c] - mu * sc;
    }
}

__global__ void gelu_bias_bf(const float* __restrict__ x, const float* __restrict__ bias,
                             u16* __restrict__ out, int n4)
{
    int stride = gridDim.x * blockDim.x;
    for (int i = blockIdx.x * blockDim.x + threadIdx.x; i < n4; i += stride) {
        int c4 = (i & 31) * 4;
        float4 v = ((const float4*)x)[i];
        ushort4 o;
        o.x = f2b(gelu_erf(v.x + bias[c4 + 0]));
        o.y = f2b(gelu_erf(v.y + bias[c4 + 1]));
        o.z = f2b(gelu_erf(v.z + bias[c4 + 2]));
        o.w = f2b(gelu_erf(v.w + bias[c4 + 3]));
        ((ushort4*)out)[i] = o;
    }
}

__global__ void hist_add(const int* __restrict__ idx, int n, int* __restrict__ cnt)
{
    int stride = gridDim.x * blockDim.x;
    for (int i = blockIdx.x * blockDim.x + threadIdx.x; i < n; i += stride)
        atomicAdd(&cnt[idx[i]], 1);
}

__global__ void hist_add2(const int* __restrict__ i0, const int* __restrict__ i1, int n,
                          int* __restrict__ c0, int* __restrict__ c1)
{
    int stride = gridDim.x * blockDim.x;
    for (int i = blockIdx.x * blockDim.x + threadIdx.x; i < n; i += stride) {
        atomicAdd(&c0[i0[i]], 1);
        atomicAdd(&c1[i1[i]], 1);
    }
}

__global__ void scan1(const int* __restrict__ cnt, int* __restrict__ ex,
                      int* __restrict__ part, int n)
{
    __shared__ int buf[1024];
    int b = blockIdx.x, t = threadIdx.x;
    int i = b * 1024 + t;
    int v = (i < n) ? cnt[i] : 0;
    buf[t] = v;
    __syncthreads();
    int incl = v;
    for (int o = 1; o < 1024; o <<= 1) {
        int tmp = (t >= o) ? buf[t - o] : 0;
        __syncthreads();
        incl += tmp;
        buf[t] = incl;
        __syncthreads();
    }
    if (i < n) ex[i] = incl - v;
    if (t == 1023) part[b] = incl;
}

__global__ void scan2(int* __restrict__ part, int nb)
{
    __shared__ int s[256];
    int t = threadIdx.x;
    if (t < nb) s[t] = part[t];
    __syncthreads();
    if (t == 0) {
        int run = 0;
        for (int b = 0; b < nb; ++b) { int x = s[b]; part[b] = run; run += x; }
        part[nb] = run;
    }
}

__global__ void scan3(int* __restrict__ indptr, const int* __restrict__ part,
                      const int* __restrict__ cnt, float* __restrict__ dinv, int n)
{
    int b = blockIdx.x, t = threadIdx.x;
    int i = b * 1024 + t;
    if (i < n) {
        indptr[i] += part[b];
        int c = cnt[i];
        dinv[i] = (c > 0) ? rsqrtf((float)c) : 0.f;
    }
    if (b == 0 && t == 0) indptr[n] = part[NB_SCAN];
}

__global__ void csr_build(const int* __restrict__ src, const int* __restrict__ dst, int n,
                          const int* __restrict__ indptr, int* __restrict__ cursor,
                          int* __restrict__ csrS)
{
    int stride = gridDim.x * blockDim.x;
    for (int e = blockIdx.x * blockDim.x + threadIdx.x; e < n; e += stride) {
        int s = src[e], d = dst[e];
        int pos = indptr[d] + atomicAdd(&cursor[d], 1);
        __builtin_nontemporal_store(s, &csrS[pos]);
    }
}

__global__ void spmm_hop(const u16* __restrict__ hin, u16* __restrict__ hout,
                         const int* __restrict__ indptr, const int* __restrict__ csrS,
                         const float* __restrict__ dinv)
{
    int gid = blockIdx.x * blockDim.x + threadIdx.x;
    int node = gid >> 6;
    int lane = gid & 63;
    if (node >= NN) return;
    float dn = dinv[node];
    int beg = indptr[node], end = indptr[node + 1];
    float a0 = 0.f, a1 = 0.f;
    int e = beg;
    for (; e + 1 < end; e += 2) {
        int s0 = csrS[e], s1 = csrS[e + 1];
        float w0 = dn * dinv[s0], w1 = dn * dinv[s1];
        ushort2 p0 = *(const ushort2*)(hin + (size_t)s0 * 128 + lane * 2);
        ushort2 p1 = *(const ushort2*)(hin + (size_t)s1 * 128 + lane * 2);
        a0 = fmaf(w0, b2f(p0.x), a0);
        a1 = fmaf(w0, b2f(p0.y), a1);
        a0 = fmaf(w1, b2f(p1.x), a0);
        a1 = fmaf(w1, b2f(p1.y), a1);
    }
    if (e < end) {
        int s0 = csrS[e];
        float w0 = dn * dinv[s0];
        ushort2 p0 = *(const ushort2*)(hin + (size_t)s0 * 128 + lane * 2);
        a0 = fmaf(w0, b2f(p0.x), a0);
        a1 = fmaf(w0, b2f(p0.y), a1);
    }
    ushort2 o;
    o.x = f2b(a0); o.y = f2b(a1);
    *(ushort2*)(hout + (size_t)node * 128 + lane * 2) = o;
}

__global__ void convTB(const float* __restrict__ in, u16* __restrict__ out,
                       int K, int Nc, int B)
{
    int per = K * Nc;
    int i = blockIdx.x * blockDim.x + threadIdx.x;
    if (i < per * B) {
        int m = i / per, r = i - m * per;
        int n = r / K, k = r - n * K;
        out[i] = f2b(in[(size_t)m * per + (size_t)k * Nc + n]);
    }
}

__global__ void fold_wT(const float* __restrict__ W0, const float* __restrict__ s,
                        u16* __restrict__ out)
{
    int i = blockIdx.x * blockDim.x + threadIdx.x;
    if (i < 512 * 544) {
        int n = i / 544, k = i - n * 544;
        out[i] = f2b(s[k] * W0[(size_t)k * 512 + n]);
    }
}

__global__ void fold_b(const float* __restrict__ W0, const float* __restrict__ b0,
                       const float* __restrict__ tv, float* __restrict__ bp)
{
    int j = blockIdx.x * blockDim.x + threadIdx.x;
    if (j < 512) {
        float s = b0[j];
        for (int k = 0; k < 544; ++k) s = fmaf(tv[k], W0[k * 512 + j], s);
        bp[j] = s;
    }
}

// ---- shared A-tile loader (128 rows x 32 k, one bf16x8 slot per call) ----
template<int AMODE>
__device__ __forceinline__ bf16x8 load_a_slot(
    const void* __restrict__ A0v, const void* __restrict__ A1v,
    const float* __restrict__ Yp, const int* __restrict__ i0s, const int* __restrict__ i1s,
    int rowOffset, const float* __restrict__ sv, const float* __restrict__ tv,
    int row, int r, int k0, int sl, int Mr, int lda)
{
    bf16x8 val = {0, 0, 0, 0, 0, 0, 0, 0};
    if (row < Mr) {
        if (AMODE == 0) {
            val = *(const bf16x8*)((const u16*)A0v + (size_t)row * lda + k0 + sl * 8);
        } else if (AMODE == 1) {
            int c = k0 + sl * 8;
            if (c < 128) {
                const float* xp = (const float*)A0v + (size_t)row * 128 + c;
                float4 x0 = *(const float4*)xp, x1 = *(const float4*)(xp + 4);
                float4 s0 = *(const float4*)(sv + c), s1 = *(const float4*)(sv + c + 4);
                float4 t0 = *(const float4*)(tv + c), t1 = *(const float4*)(tv + c + 4);
                float4 a = make_float4(fmaf(x0.x,s0.x,t0.x), fmaf(x0.y,s0.y,t0.y),
                                       fmaf(x0.z,s0.z,t0.z), fmaf(x0.w,s0.w,t0.w));
                float4 b = make_float4(fmaf(x1.x,s1.x,t1.x), fmaf(x1.y,s1.y,t1.y),
                                       fmaf(x1.z,s1.z,t1.z), fmaf(x1.w,s1.w,t1.w));
                val = cvt8(a, b);
            } else {
                val = *(const bf16x8*)((const u16*)A1v + (size_t)row * 128 + (c - 128));
            }
        } else if (AMODE == 3) {
            int c = k0 + sl * 8;
            const float* xp = (const float*)A0v + (size_t)row * 128 + c;
            float4 x0 = *(const float4*)xp, x1 = *(const float4*)(xp + 4);
            float4 s0 = *(const float4*)(sv + c), s1 = *(const float4*)(sv + c + 4);
            float4 t0 = *(const float4*)(tv + c), t1 = *(const float4*)(tv + c + 4);
            float4 a = make_float4(fmaf(x0.x,s0.x,t0.x), fmaf(x0.y,s0.y,t0.y),
                                   fmaf(x0.z,s0.z,t0.z), fmaf(x0.w,s0.w,t0.w));
            float4 b = make_float4(fmaf(x1.x,s1.x,t1.x), fmaf(x1.y,s1.y,t1.y),
                                   fmaf(x1.z,s1.z,t1.z), fmaf(x1.w,s1.w,t1.w));
            val = cvt8(a, b);
        } else { // AMODE 2: Omega gather
            int seg = k0 >> 7;
            int c = (k0 & 127) + sl * 8;
            if (seg == 0) {
                val = *(const bf16x8*)((const u16*)A0v + (size_t)i0s[r] * 128 + c);
            } else if (seg == 1) {
                val = *(const bf16x8*)((const u16*)A0v + (size_t)i1s[r] * 128 + c);
            } else if (seg == 2) {
                const float* xp = (const float*)A1v + (size_t)i0s[r] * 128 + c;
                val = cvt8(*(const float4*)xp, *(const float4*)(xp + 4));
            } else if (seg == 3) {
                const float* xp = (const float*)A1v + (size_t)i1s[r] * 128 + c;
                val = cvt8(*(const float4*)xp, *(const float4*)(xp + 4));
            } else {
                const float* yp = Yp + (size_t)(rowOffset + row) * 32 + sl * 8;
                val = cvt8(*(const float4*)yp, *(const float4*)(yp + 4));
            }
        }
    }
    return val;
}

// ------------- 4-wave MFMA GEMM: tile 128x128, BK=32 (N<=128 GEMMs)
template<int AMODE, int ACT, int ACCUM, int OUTBF>
__launch_bounds__(256, 2)
__global__ void gemm_mfma(const void* __restrict__ A0v, const void* __restrict__ A1v,
                          const float* __restrict__ Yp,
                          const int* __restrict__ I0, const int* __restrict__ I1,
                          int rowOffset,
                          const float* __restrict__ sv, const float* __restrict__ tv,
                          const u16* __restrict__ Wb, const float* __restrict__ bias,
                          void* __restrict__ Cv, int Mr, int Kd, int Nc, int lda)
{
    __shared__ __align__(16) u16 As[128 * 32];
    __shared__ __align__(16) u16 Bs[128 * 32];
    __shared__ int i0s[128], i1s[128];

    const int t = threadIdx.x;
    const int lane = t & 63;
    const int wid = t >> 6;
    const int wm = wid >> 1, wn = wid & 1;
    const int lb = lane & 15, lh = lane >> 4;
    const int row0 = blockIdx.x * 128;
    const int colb = blockIdx.y * 128;

    if (AMODE == 2) {
        if (t < 128) {
            int r = row0 + t;
            i0s[t] = (r < Mr) ? I0[rowOffset + r] : 0;
        } else {
            int r = row0 + (t - 128);
            i1s[t - 128] = (r < Mr) ? I1[rowOffset + r] : 0;
        }
    }

    f32x4 acc[4][4];
#pragma unroll
    for (int i = 0; i < 4; ++i)
#pragma unroll
        for (int j = 0; j < 4; ++j) acc[i][j] = (f32x4){0.f, 0.f, 0.f, 0.f};

    for (int k0 = 0; k0 < Kd; k0 += 32) {
        __syncthreads();
#pragma unroll
        for (int h = 0; h < 2; ++h) {
            int s = t + h * 256;
            int r = s >> 2, sl = s & 3;
            bf16x8 val = load_a_slot<AMODE>(A0v, A1v, Yp, i0s, i1s, rowOffset, sv, tv,
                                            row0 + r, r, k0, sl, Mr, lda);
            *(bf16x8*)&As[r * 32 + ((sl ^ ((r >> 1) & 3)) << 3)] = val;
        }
#pragma unroll
        for (int h = 0; h < 2; ++h) {
            int s = t + h * 256;
            int n = s >> 2, sl = s & 3;
            bf16x8 val = *(const bf16x8*)(Wb + (size_t)(colb + n) * Kd + k0 + sl * 8);
            *(bf16x8*)&Bs[n * 32 + ((sl ^ ((n >> 1) & 3)) << 3)] = val;
        }
        __syncthreads();
        bf16x8 af[4], bfr[4];
#pragma unroll
        for (int i = 0; i < 4; ++i) {
            int r = wm * 64 + i * 16 + lb;
            af[i] = *(const bf16x8*)&As[r * 32 + ((lh ^ ((r >> 1) & 3)) << 3)];
        }
#pragma unroll
        for (int j = 0; j < 4; ++j) {
            int n = wn * 64 + j * 16 + lb;
            bfr[j] = *(const bf16x8*)&Bs[n * 32 + ((lh ^ ((n >> 1) & 3)) << 3)];
        }
#pragma unroll
        for (int i = 0; i < 4; ++i)
#pragma unroll
            for (int j = 0; j < 4; ++j)
                acc[i][j] = __builtin_amdgcn_mfma_f32_16x16x32_bf16(af[i], bfr[j], acc[i][j], 0, 0, 0);
    }

#pragma unroll
    for (int i = 0; i < 4; ++i) {
#pragma unroll
        for (int j = 0; j < 4; ++j) {
            int col = colb + wn * 64 + j * 16 + lb;
#pragma unroll
            for (int r = 0; r < 4; ++r) {
                int row = row0 + wm * 64 + i * 16 + lh * 4 + r;
                if (row < Mr) {
                    size_t off = (size_t)row * Nc + col;
                    float v = acc[i][j][r];
                    if (ACCUM) v += ((const float*)Cv)[off];
                    if (ACT) v = gelu_erf(v + bias[col]);
                    if (OUTBF) ((u16*)Cv)[off] = f2b(v);
                    else       ((float*)Cv)[off] = v;
                }
            }
        }
    }
}

// ------------- 8-wave MFMA GEMM: tile 128x256, BK=32 (wide-N GEMMs)
template<int AMODE, int ACT, int OUTBF>
__launch_bounds__(512, 4)
__global__ void gemm_wide(const void* __restrict__ A0v, const void* __restrict__ A1v,
                          const float* __restrict__ Yp,
                          const int* __restrict__ I0, const int* __restrict__ I1,
                          int rowOffset,
                          const float* __restrict__ sv, const float* __restrict__ tv,
                          const u16* __restrict__ Wb, const float* __restrict__ bias,
                          void* __restrict__ Cv, int Mr, int Kd, int Nc)
{
    __shared__ __align__(16) u16 As[128 * 32];
    __shared__ __align__(16) u16 Bs[256 * 32];
    __shared__ int i0s[128], i1s[128];

    const int t = threadIdx.x;
    const int lane = t & 63;
    const int wid = t >> 6;           // 0..7
    const int wm = wid >> 2, wn = wid & 3;
    const int lb = lane & 15, lh = lane >> 4;
    const int row0 = blockIdx.x * 128;
    const int colb = blockIdx.y * 256;

    if (AMODE == 2) {
        if (t < 128) {
            int r = row0 + t;
            i0s[t] = (r < Mr) ? I0[rowOffset + r] : 0;
        } else if (t < 256) {
            int r = row0 + (t - 128);
            i1s[t - 128] = (r < Mr) ? I1[rowOffset + r] : 0;
        }
    }

    f32x4 acc[4][4];
#pragma unroll
    for (int i = 0; i < 4; ++i)
#pragma unroll
        for (int j = 0; j < 4; ++j) acc[i][j] = (f32x4){0.f, 0.f, 0.f, 0.f};

    for (int k0 = 0; k0 < Kd; k0 += 32) {
        __syncthreads();
        {   // A: 512 slots, 1 per thread
            int r = t >> 2, sl = t & 3;
            bf16x8 val = load_a_slot<AMODE>(A0v, A1v, Yp, i0s, i1s, rowOffset, sv, tv,
                                            row0 + r, r, k0, sl, Mr, 0);
            *(bf16x8*)&As[r * 32 + ((sl ^ ((r >> 1) & 3)) << 3)] = val;
        }
#pragma unroll
        for (int h = 0; h < 2; ++h) {  // B: 1024 slots, 2 per thread
            int s = t + h * 512;
            int n = s >> 2, sl = s & 3;
            bf16x8 val = *(const bf16x8*)(Wb + (size_t)(colb + n) * Kd + k0 + sl * 8);
            *(bf16x8*)&Bs[n * 32 + ((sl ^ ((n >> 1) & 3)) << 3)] = val;
        }
        __syncthreads();
        bf16x8 af[4], bfr[4];
#pragma unroll
        for (int i = 0; i < 4; ++i) {
            int r = wm * 64 + i * 16 + lb;
            af[i] = *(const bf16x8*)&As[r * 32 + ((lh ^ ((r >> 1) & 3)) << 3)];
        }
#pragma unroll
        for (int j = 0; j < 4; ++j) {
            int n = wn * 64 + j * 16 + lb;
            bfr[j] = *(const bf16x8*)&Bs[n * 32 + ((lh ^ ((n >> 1) & 3)) << 3)];
        }
#pragma unroll
        for (int i = 0; i < 4; ++i)
#pragma unroll
            for (int j = 0; j < 4; ++j)
                acc[i][j] = __builtin_amdgcn_mfma_f32_16x16x32_bf16(af[i], bfr[j], acc[i][j], 0, 0, 0);
    }

#pragma unroll
    for (int i = 0; i < 4; ++i) {
#pragma unroll
        for (int j = 0; j < 4; ++j) {
            int col = colb + wn * 64 + j * 16 + lb;
#pragma unroll
            for (int r = 0; r < 4; ++r) {
                int row = row0 + wm * 64 + i * 16 + lh * 4 + r;
                if (row < Mr) {
                    size_t off = (size_t)row * Nc + col;
                    float v = acc[i][j][r];
                    if (ACT) v = gelu_erf(v + bias[col]);
                    if (OUTBF) ((u16*)Cv)[off] = f2b(v);
                    else       ((float*)Cv)[off] = v;
                }
            }
        }
    }
}

// ------------- edge layer-2 + sigmoid head fused: o1[m,512] @ elW1 -> gelu -> dot elEW -> sigmoid
__launch_bounds__(512, 4)
__global__ void gemm_head(const u16* __restrict__ A0, const u16* __restrict__ Wb,
                          const float* __restrict__ bias,   // elb1 [256]
                          const float* __restrict__ eW,     // elEW [256]
                          const float* __restrict__ eb,     // elEb [1]
                          float* __restrict__ outp, int outOffset, int Mr)
{
    __shared__ __align__(16) u16 As[128 * 32];
    __shared__ __align__(16) u16 Bs[256 * 32];
    __shared__ float bls[256], ews[256];
    __shared__ float sred[4][128];

    const int t = threadIdx.x;
    const int lane = t & 63;
    const int wid = t >> 6;
    const int wm = wid >> 2, wn = wid & 3;
    const int lb = lane & 15, lh = lane >> 4;
    const int row0 = blockIdx.x * 128;
    const int Kd = 512;

    if (t < 256) { bls[t] = bias[t]; ews[t] = eW[t]; }

    f32x4 acc[4][4];
#pragma unroll
    for (int i = 0; i < 4; ++i)
#pragma unroll
        for (int j = 0; j < 4; ++j) acc[i][j] = (f32x4){0.f, 0.f, 0.f, 0.f};

    for (int k0 = 0; k0 < Kd; k0 += 32) {
        __syncthreads();
        {
            int r = t >> 2, sl = t & 3;
            int row = row0 + r;
            bf16x8 val = {0,0,0,0,0,0,0,0};
            if (row < Mr) val = *(const bf16x8*)(A0 + (size_t)row * 512 + k0 + sl * 8);
            *(bf16x8*)&As[r * 32 + ((sl ^ ((r >> 1) & 3)) << 3)] = val;
        }
#pragma unroll
        for (int h = 0; h < 2; ++h) {
            int s = t + h * 512;
            int n = s >> 2, sl = s & 3;
            bf16x8 val = *(const bf16x8*)(Wb + (size_t)n * Kd + k0 + sl * 8);
            *(bf16x8*)&Bs[n * 32 + ((sl ^ ((n >> 1) & 3)) << 3)] = val;
        }
        __syncthreads();
        bf16x8 af[4], bfr[4];
#pragma unroll
        for (int i = 0; i < 4; ++i) {
            int r = wm * 64 + i * 16 + lb;
            af[i] = *(const bf16x8*)&As[r * 32 + ((lh ^ ((r >> 1) & 3)) << 3)];
        }
#pragma unroll
        for (int j = 0; j < 4; ++j) {
            int n = wn * 64 + j * 16 + lb;
            bfr[j] = *(const bf16x8*)&Bs[n * 32 + ((lh ^ ((n >> 1) & 3)) << 3)];
        }
#pragma unroll
        for (int i = 0; i < 4; ++i)
#pragma unroll
            for (int j = 0; j < 4; ++j)
                acc[i][j] = __builtin_amdgcn_mfma_f32_16x16x32_bf16(af[i], bfr[j], acc[i][j], 0, 0, 0);
    }

    // head epilogue: per-row sum of gelu(o2)*eW over 256 cols
#pragma unroll
    for (int i = 0; i < 4; ++i) {
#pragma unroll
        for (int r = 0; r < 4; ++r) {
            float p = 0.f;
#pragma unroll
            for (int j = 0; j < 4; ++j) {
                int col = wn * 64 + j * 16 + lb;
                p += gelu_erf(acc[i][j][r] + bls[col]) * ews[col];
            }
            p += __shfl_xor(p, 1);
            p += __shfl_xor(p, 2);
            p += __shfl_xor(p, 4);
            p += __shfl_xor(p, 8);
            if (lb == 0) sred[wn][wm * 64 + i * 16 + lh * 4 + r] = p;
        }
    }
    __syncthreads();
    if (t < 128) {
        int row = row0 + t;
        if (row < Mr) {
            float s = sred[0][t] + sred[1][t] + sred[2][t] + sred[3][t] + eb[0];
            outp[outOffset + row] = 1.f / (1.f + expf(-s));
        }
    }
}

// logits = cl @ endW + endB ; softmax over 8 ; one wave per row
__global__ void node_head(const float* __restrict__ cl, const float* __restrict__ Wend,
                          const float* __restrict__ bend, float* __restrict__ out, int m)
{
    __shared__ float WsT[8 * 128];
    __shared__ float bs[8];
    int t = threadIdx.x;
    for (int i = t; i < 1024; i += 256) {
        int k = i >> 3, j = i & 7;
        WsT[j * 128 + k] = Wend[i];
    }
    if (t < 8) bs[t] = bend[t];
    __syncthreads();
    int gid = blockIdx.x * 256 + t;
    int wave = gid >> 6, lane = gid & 63;
    if (wave >= m) return;
    float v0 = cl[(size_t)wave * 128 + lane];
    float v1 = cl[(size_t)wave * 128 + lane + 64];
    float lg[8];
#pragma unroll
    for (int j = 0; j < 8; ++j) {
        float p = v0 * WsT[j * 128 + lane] + v1 * WsT[j * 128 + lane + 64];
#pragma unroll
        for (int o = 32; o; o >>= 1) p += __shfl_down(p, o);
        lg[j] = p;
    }
    if (lane == 0) {
        float mx = -1e30f;
#pragma unroll
        for (int j = 0; j < 8; ++j) { lg[j] += bs[j]; mx = fmaxf(mx, lg[j]); }
        float s = 0.f;
#pragma unroll
        for (int j = 0; j < 8; ++j) { lg[j] = expf(lg[j] - mx); s += lg[j]; }
        float inv = 1.f / s;
#pragma unroll
        for (int j = 0; j < 8; ++j) out[(size_t)wave * 8 + j] = lg[j] * inv;
    }
}

extern "C" void kernel_launch(void* const* d_in, const int* in_sizes, int n_in,
                              void* d_out, int out_size, void* d_ws, size_t ws_size,
                              hipStream_t stream)
{
    const float* X    = (const float*)d_in[0];
    const float* Y    = (const float*)d_in[1];
    const int*   EI   = (const int*)d_in[2];
    const int*   I0   = (const int*)d_in[3];
    const int*   I1   = (const int*)d_in[4];
    const float* bnG  = (const float*)d_in[5];
    const float* bnB  = (const float*)d_in[6];
    const float* Wlin = (const float*)d_in[7];
    const float* blin = (const float*)d_in[8];
    const float* tagWs= (const float*)d_in[9];
    const float* tagB = (const float*)d_in[10];
    const float* nlW0 = (const float*)d_in[11];
    const float* nlb0 = (const float*)d_in[12];
    const float* nlW1 = (const float*)d_in[13];
    const float* nlb1 = (const float*)d_in[14];
    const float* clW  = (const float*)d_in[15];
    const float* clb  = (const float*)d_in[16];
    const float* endW = (const float*)d_in[17];
    const float* endB = (const float*)d_in[18];
    const float* beG  = (const float*)d_in[19];
    const float* beB  = (const float*)d_in[20];
    const float* elW0 = (const float*)d_in[21];
    const float* elb0 = (const float*)d_in[22];
    const float* elW1 = (const float*)d_in[23];
    const float* elb1 = (const float*)d_in[24];
    const float* elEW = (const float*)d_in[25];
    const float* elEb = (const float*)d_in[26];

    const int N = NN, E = NE, P = NP;

    char* w = (char*)d_ws;
    size_t off = 0;
    auto alloc = [&](size_t bytes) -> void* {
        void* p = w + off;
        off += (bytes + 255) & ~(size_t)255;
        return p;
    };

    // --- zeroed region ---
    size_t zeroBytes = (size_t)(544 + 544 + 128 + 128) * 4 + (size_t)4 * N * 4;
    char* zr = (char*)alloc(zeroBytes);
    float* statS = (float*)zr;
    float* statQ = statS + 544;
    float* nodeS = statQ + 544;
    float* nodeQ = nodeS + 128;
    int* cnt    = (int*)(nodeQ + 128);
    int* cursor = cnt + N;
    int* cnt0   = cursor + N;
    int* cnt1   = cnt0 + N;

    int*   indptr = (int*)alloc((size_t)(N + 1) * 4);
    int*   part   = (int*)alloc((size_t)(NB_SCAN + 1) * 4);
    float* dinv   = (float*)alloc((size_t)N * 4);
    int*   csrS   = (int*)alloc((size_t)E * 4);
    float* sNode  = (float*)alloc(128 * 4);
    float* tNode  = (float*)alloc(128 * 4);
    float* sEdge  = (float*)alloc(544 * 4);
    float* tEdge  = (float*)alloc(544 * 4);
    float* b0p    = (float*)alloc(512 * 4);
    u16* Wlinb  = (u16*)alloc((size_t)128 * 128 * 2);
    u16* tagWsb = (u16*)alloc((size_t)7 * 128 * 128 * 2);
    u16* nlW0b  = (u16*)alloc((size_t)256 * 256 * 2);
    u16* nlW1b  = (u16*)alloc((size_t)128 * 256 * 2);
    u16* clWb   = (u16*)alloc((size_t)128 * 128 * 2);
    u16* elW1b  = (u16*)alloc((size_t)256 * 512 * 2);
    u16* W0pb   = (u16*)alloc((size_t)512 * 544 * 2);
    // big buffers: hA | hB | outT contiguous
    u16*   hA   = (u16*)alloc((size_t)N * 128 * 2);   // h ping / aEmb
    u16*   hB   = (u16*)alloc((size_t)N * 128 * 2);   // h pong / houtb / edge chunk lo
    float* outT = (float*)alloc((size_t)N * 128 * 4); // TAG acc / a256+clbuf / edge chunk hi

    if (ws_size < off) return;   // diagnostic: clean absmax fail instead of a fault

    u16*   aEmb  = hA;
    u16*   houtb = hB;
    float* out_nodes = (float*)d_out;
    float* out_epred = (float*)d_out + (size_t)N * 8;

    hipMemsetAsync(zr, 0, zeroBytes, stream);

    // ---- weight conversions (transposed bf16) ----
    convTB<<<(128*128 + 255)/256, 256, 0, stream>>>(Wlin, Wlinb, 128, 128, 1);
    convTB<<<(7*128*128 + 255)/256, 256, 0, stream>>>(tagWs, tagWsb, 128, 128, 7);
    convTB<<<(256*256 + 255)/256, 256, 0, stream>>>(nlW0, nlW0b, 256, 256, 1);
    convTB<<<(256*128 + 255)/256, 256, 0, stream>>>(nlW1, nlW1b, 256, 128, 1);
    convTB<<<(128*128 + 255)/256, 256, 0, stream>>>(clW, clWb, 128, 128, 1);
    convTB<<<(512*256 + 255)/256, 256, 0, stream>>>(elW1, elW1b, 512, 256, 1);

    // ---- node BN stats ----
    col_stats<0><<<1024, 256, 0, stream>>>(X, N, 7, nullptr, nullptr, nodeS, nodeQ, 0, 0);
    bn_finalize<<<1, 128, 0, stream>>>(nodeS, nodeQ, bnG, bnB, sNode, tNode, 128, (float)N, 1e-5f);

    // ---- tag linear: hA = bf16(gelu(BN(X) @ Wlin + blin)) ----
    dim3 g1((N + 127) / 128, 1);
    gemm_mfma<3, 1, 0, 1><<<g1, 256, 0, stream>>>(X, nullptr, nullptr, nullptr, nullptr, 0,
                                                  sNode, tNode, Wlinb, blin, hA, N, 128, 128, 128);

    // ---- graph prep ----
    hist_add<<<2048, 256, 0, stream>>>(EI + E, E, cnt);
    hist_add2<<<1024, 256, 0, stream>>>(I0, I1, P, cnt0, cnt1);
    scan1<<<NB_SCAN, 1024, 0, stream>>>(cnt, indptr, part, N);
    scan2<<<1, 256, 0, stream>>>(part, NB_SCAN);
    scan3<<<NB_SCAN, 1024, 0, stream>>>(indptr, part, cnt, dinv, N);
    csr_build<<<2048, 256, 0, stream>>>(EI, EI + E, E, indptr, cursor, csrS);

    // ---- TAGConv ----
    gemm_mfma<0, 0, 0, 0><<<g1, 256, 0, stream>>>(hA, nullptr, nullptr, nullptr, nullptr, 0,
                                                  nullptr, nullptr, tagWsb, nullptr, outT, N, 128, 128, 128);
    u16* cur = hA; u16* nxt = hB;
    for (int k = 1; k <= KHOPS; ++k) {
        spmm_hop<<<(N * 64 + 255) / 256, 256, 0, stream>>>(cur, nxt, indptr, csrS, dinv);
        gemm_mfma<0, 0, 1, 0><<<g1, 256, 0, stream>>>(nxt, nullptr, nullptr, nullptr, nullptr, 0,
                                                      nullptr, nullptr, tagWsb + (size_t)k*128*128,
                                                      nullptr, outT, N, 128, 128, 128);
        u16* tmp = cur; cur = nxt; nxt = tmp;
    }
    gelu_bias_bf<<<2048, 256, 0, stream>>>(outT, tagB, houtb, N * 128 / 4);

    // ---- node MLP; a256/clbuf alias outT ----
    u16*   a256  = (u16*)outT;     // [N,256] bf16 = 51.2 MB
    float* clbuf = outT;           // [N,128] f32 reuses outT after a256 dies
    {
        dim3 gA((N + 127) / 128, 1);    // N=256 in one wide tile
        gemm_wide<1, 1, 1><<<gA, 512, 0, stream>>>(X, houtb, nullptr, nullptr, nullptr, 0,
                                                   sNode, tNode, nlW0b, nlb0, a256, N, 256, 256);
        dim3 gB((N + 127) / 128, 1);
        gemm_mfma<0, 1, 0, 1><<<gB, 256, 0, stream>>>(a256, nullptr, nullptr, nullptr, nullptr, 0,
                                                      nullptr, nullptr, nlW1b, nlb1, aEmb, N, 256, 128, 256);
        gemm_mfma<0, 1, 0, 0><<<gB, 256, 0, stream>>>(aEmb, nullptr, nullptr, nullptr, nullptr, 0,
                                                      nullptr, nullptr, clWb, clb, clbuf, N, 128, 128, 128);
        node_head<<<(N + 3) / 4, 256, 0, stream>>>(clbuf, endW, endB, out_nodes, N);
    }

    // ---- edge BN stats (count-weighted, exact) ----
    col_stats<1><<<1024, 256, 0, stream>>>(aEmb, N, 7, cnt0, cnt1, statS, statQ, 0, 128);
    col_stats<0><<<1024, 256, 0, stream>>>(X,    N, 7, cnt0, cnt1, statS, statQ, 256, 384);
    col_stats<0><<<1024, 256, 0, stream>>>(Y,    P, 5, nullptr, nullptr, statS, statQ, 512, 0);
    bn_finalize<<<3, 256, 0, stream>>>(statS, statQ, beG, beB, sEdge, tEdge, 544, (float)P, 1.0f);
    fold_wT<<<(512*544 + 255)/256, 256, 0, stream>>>(elW0, sEdge, W0pb);
    fold_b<<<2, 256, 0, stream>>>(elW0, elb0, tEdge, b0p);

    // ---- edge MLP: o1 spans hB+outT (76.8 MB); L2+head fused ----
    u16* o1 = hB;                               // [ECHK,512] bf16
    for (int pb = 0; pb < P; pb += ECHK) {
        int m = (P - pb < ECHK) ? (P - pb) : ECHK;
        dim3 gA((m + 127) / 128, 2);
        gemm_wide<2, 1, 1><<<gA, 512, 0, stream>>>(aEmb, X, Y, I0, I1, pb,
                                                   nullptr, nullptr, W0pb, b0p, o1, m, 544, 512);
        dim3 gB((m + 127) / 128, 1);
        gemm_head<<<gB, 512, 0, stream>>>(o1, elW1b, elb1, elEW, elEb, out_epred, pb, m);
    }
}

// Round 8
// 2338.785 us; speedup vs baseline: 4.6843x; 1.0988x over previous
//
#include <hip/hip_runtime.h>
#include <math.h>

#define NN 100000
#define NE 1600000
#define NP 500000
#define KHOPS 6
#define ECHK 50000          // edge chunk rows; o1 [ECHK,512] bf16 = 51.2 MB = outT
#define NB_SCAN ((NN + 1023) / 1024)

typedef unsigned short u16;
typedef short bf16x8 __attribute__((ext_vector_type(8)));
typedef float f32x4 __attribute__((ext_vector_type(4)));

__device__ __forceinline__ float gelu_erf(float x) {
    return 0.5f * x * (1.0f + erff(x * 0.70710678118654752f));
}
__device__ __forceinline__ float b2f(u16 u) {
    return __uint_as_float(((unsigned int)u) << 16);
}
__device__ __forceinline__ u16 f2b(float f) {
    unsigned int x = __float_as_uint(f);
    return (u16)((x + 0x7FFFu + ((x >> 16) & 1u)) >> 16);
}
__device__ __forceinline__ bf16x8 cvt8(float4 a, float4 b) {
    bf16x8 v;
    v[0]=(short)f2b(a.x); v[1]=(short)f2b(a.y); v[2]=(short)f2b(a.z); v[3]=(short)f2b(a.w);
    v[4]=(short)f2b(b.x); v[5]=(short)f2b(b.y); v[6]=(short)f2b(b.z); v[7]=(short)f2b(b.w);
    return v;
}

// ---------------- column statistics (optionally weighted by up to 2 int count vectors)
template<int BF>
__global__ void col_stats(const void* __restrict__ Matv, int rows, int lc,
                          const int* __restrict__ w0, const int* __restrict__ w1,
                          float* __restrict__ sums, float* __restrict__ sumsq,
                          int base0, int base1)
{
    __shared__ float red[256];
    const int t = threadIdx.x;
    const int C = 1 << lc;
    const long total = (long)rows << lc;
    const long stride = (long)gridDim.x * 256;
    float s0 = 0.f, q0 = 0.f, s1 = 0.f, q1 = 0.f;
    for (long idx = (long)blockIdx.x * 256 + t; idx < total; idx += stride) {
        int r = (int)(idx >> lc);
        float v = BF ? b2f(((const u16*)Matv)[idx]) : ((const float*)Matv)[idx];
        float f0 = w0 ? (float)w0[r] : 1.0f;
        s0 += f0 * v;
        q0 += f0 * v * v;
        if (w1) {
            float f1 = (float)w1[r];
            s1 += f1 * v;
            q1 += f1 * v * v;
        }
    }
    red[t] = s0; __syncthreads();
    if (t < C) { float x = 0.f; for (int k = t; k < 256; k += C) x += red[k]; atomicAdd(&sums[base0 + t], x); }
    __syncthreads();
    red[t] = q0; __syncthreads();
    if (t < C) { float x = 0.f; for (int k = t; k < 256; k += C) x += red[k]; atomicAdd(&sumsq[base0 + t], x); }
    __syncthreads();
    if (w1) {
        red[t] = s1; __syncthreads();
        if (t < C) { float x = 0.f; for (int k = t; k < 256; k += C) x += red[k]; atomicAdd(&sums[base1 + t], x); }
        __syncthreads();
        red[t] = q1; __syncthreads();
        if (t < C) { float x = 0.f; for (int k = t; k < 256; k += C) x += red[k]; atomicAdd(&sumsq[base1 + t], x); }
    }
}

__global__ void bn_finalize(const float* __restrict__ sums, const float* __restrict__ sumsq,
                            const float* __restrict__ g, const float* __restrict__ b,
                            float* __restrict__ s, float* __restrict__ t,
                            int C, float count, float eps)
{
    int c = blockIdx.x * blockDim.x + threadIdx.x;
    if (c < C) {
        float mu = sums[c] / count;
        float var = sumsq[c] / count - mu * mu;
        float sc = g[c] * rsqrtf(var + eps);
        s[c] = sc;
        t[c] = b[c] - mu * sc;
    }
}

__global__ void hist_add(const int* __restrict__ idx, int n, int* __restrict__ cnt)
{
    int stride = gridDim.x * blockDim.x;
    for (int i = blockIdx.x * blockDim.x + threadIdx.x; i < n; i += stride)
        atomicAdd(&cnt[idx[i]], 1);
}

__global__ void hist_add2(const int* __restrict__ i0, const int* __restrict__ i1, int n,
                          int* __restrict__ c0, int* __restrict__ c1)
{
    int stride = gridDim.x * blockDim.x;
    for (int i = blockIdx.x * blockDim.x + threadIdx.x; i < n; i += stride) {
        atomicAdd(&c0[i0[i]], 1);
        atomicAdd(&c1[i1[i]], 1);
    }
}

__global__ void scan1(const int* __restrict__ cnt, int* __restrict__ ex,
                      int* __restrict__ part, int n)
{
    __shared__ int buf[1024];
    int b = blockIdx.x, t = threadIdx.x;
    int i = b * 1024 + t;
    int v = (i < n) ? cnt[i] : 0;
    buf[t] = v;
    __syncthreads();
    int incl = v;
    for (int o = 1; o < 1024; o <<= 1) {
        int tmp = (t >= o) ? buf[t - o] : 0;
        __syncthreads();
        incl += tmp;
        buf[t] = incl;
        __syncthreads();
    }
    if (i < n) ex[i] = incl - v;
    if (t == 1023) part[b] = incl;
}

__global__ void scan2(int* __restrict__ part, int nb)
{
    __shared__ int s[256];
    int t = threadIdx.x;
    if (t < nb) s[t] = part[t];
    __syncthreads();
    if (t == 0) {
        int run = 0;
        for (int b = 0; b < nb; ++b) { int x = s[b]; part[b] = run; run += x; }
        part[nb] = run;
    }
}

__global__ void scan3(int* __restrict__ indptr, const int* __restrict__ part,
                      const int* __restrict__ cnt, float* __restrict__ dinv, int n)
{
    int b = blockIdx.x, t = threadIdx.x;
    int i = b * 1024 + t;
    if (i < n) {
        indptr[i] += part[b];
        int c = cnt[i];
        dinv[i] = (c > 0) ? rsqrtf((float)c) : 0.f;
    }
    if (b == 0 && t == 0) indptr[n] = part[NB_SCAN];
}

__global__ void csr_build(const int* __restrict__ src, const int* __restrict__ dst, int n,
                          const int* __restrict__ indptr, int* __restrict__ cursor,
                          int* __restrict__ csrS)
{
    int stride = gridDim.x * blockDim.x;
    for (int e = blockIdx.x * blockDim.x + threadIdx.x; e < n; e += stride) {
        int s = src[e], d = dst[e];
        int pos = indptr[d] + atomicAdd(&cursor[d], 1);
        csrS[pos] = s;
    }
}

// hout[n, 2l..2l+1] via ushort2; 4-edge unroll
__global__ void spmm_hop(const u16* __restrict__ hin, u16* __restrict__ hout,
                         const int* __restrict__ indptr, const int* __restrict__ csrS,
                         const float* __restrict__ dinv)
{
    int gid = blockIdx.x * blockDim.x + threadIdx.x;
    int node = gid >> 6;
    int lane = gid & 63;
    if (node >= NN) return;
    float dn = dinv[node];
    int beg = indptr[node], end = indptr[node + 1];
    float a0 = 0.f, a1 = 0.f;
    int e = beg;
    for (; e + 3 < end; e += 4) {
        int s0 = csrS[e], s1 = csrS[e + 1], s2 = csrS[e + 2], s3 = csrS[e + 3];
        float w0 = dn * dinv[s0], w1 = dn * dinv[s1];
        float w2 = dn * dinv[s2], w3 = dn * dinv[s3];
        ushort2 p0 = *(const ushort2*)(hin + (size_t)s0 * 128 + lane * 2);
        ushort2 p1 = *(const ushort2*)(hin + (size_t)s1 * 128 + lane * 2);
        ushort2 p2 = *(const ushort2*)(hin + (size_t)s2 * 128 + lane * 2);
        ushort2 p3 = *(const ushort2*)(hin + (size_t)s3 * 128 + lane * 2);
        a0 = fmaf(w0, b2f(p0.x), a0); a1 = fmaf(w0, b2f(p0.y), a1);
        a0 = fmaf(w1, b2f(p1.x), a0); a1 = fmaf(w1, b2f(p1.y), a1);
        a0 = fmaf(w2, b2f(p2.x), a0); a1 = fmaf(w2, b2f(p2.y), a1);
        a0 = fmaf(w3, b2f(p3.x), a0); a1 = fmaf(w3, b2f(p3.y), a1);
    }
    for (; e < end; ++e) {
        int s0 = csrS[e];
        float w0 = dn * dinv[s0];
        ushort2 p0 = *(const ushort2*)(hin + (size_t)s0 * 128 + lane * 2);
        a0 = fmaf(w0, b2f(p0.x), a0);
        a1 = fmaf(w0, b2f(p0.y), a1);
    }
    ushort2 o;
    o.x = f2b(a0); o.y = f2b(a1);
    *(ushort2*)(hout + (size_t)node * 128 + lane * 2) = o;
}

__global__ void convTB(const float* __restrict__ in, u16* __restrict__ out,
                       int K, int Nc, int B)
{
    int per = K * Nc;
    int i = blockIdx.x * blockDim.x + threadIdx.x;
    if (i < per * B) {
        int m = i / per, r = i - m * per;
        int n = r / K, k = r - n * K;
        out[i] = f2b(in[(size_t)m * per + (size_t)k * Nc + n]);
    }
}

// plain fp32 -> bf16 convert (no transpose), float4-vectorized
__global__ void convB(const float* __restrict__ in, u16* __restrict__ out, int n4)
{
    int stride = gridDim.x * blockDim.x;
    for (int i = blockIdx.x * blockDim.x + threadIdx.x; i < n4; i += stride) {
        float4 v = ((const float4*)in)[i];
        ushort4 o;
        o.x = f2b(v.x); o.y = f2b(v.y); o.z = f2b(v.z); o.w = f2b(v.w);
        ((ushort4*)out)[i] = o;
    }
}

__global__ void fold_wT(const float* __restrict__ W0, const float* __restrict__ s,
                        u16* __restrict__ out)
{
    int i = blockIdx.x * blockDim.x + threadIdx.x;
    if (i < 512 * 544) {
        int n = i / 544, k = i - n * 544;
        out[i] = f2b(s[k] * W0[(size_t)k * 512 + n]);
    }
}

__global__ void fold_b(const float* __restrict__ W0, const float* __restrict__ b0,
                       const float* __restrict__ tv, float* __restrict__ bp)
{
    int j = blockIdx.x * blockDim.x + threadIdx.x;
    if (j < 512) {
        float s = b0[j];
        for (int k = 0; k < 544; ++k) s = fmaf(tv[k], W0[k * 512 + j], s);
        bp[j] = s;
    }
}

// ---- shared A-tile loader ----
template<int AMODE>
__device__ __forceinline__ bf16x8 load_a_slot(
    const void* __restrict__ A0v, const void* __restrict__ A1v,
    const float* __restrict__ Yp, const int* __restrict__ i0s, const int* __restrict__ i1s,
    int rowOffset, const float* __restrict__ sv, const float* __restrict__ tv,
    int row, int r, int k0, int sl, int Mr, int lda)
{
    bf16x8 val = {0, 0, 0, 0, 0, 0, 0, 0};
    if (row < Mr) {
        if (AMODE == 0) {
            val = *(const bf16x8*)((const u16*)A0v + (size_t)row * lda + k0 + sl * 8);
        } else if (AMODE == 1) {
            int c = k0 + sl * 8;
            if (c < 128) {
                const float* xp = (const float*)A0v + (size_t)row * 128 + c;
                float4 x0 = *(const float4*)xp, x1 = *(const float4*)(xp + 4);
                float4 s0 = *(const float4*)(sv + c), s1 = *(const float4*)(sv + c + 4);
                float4 t0 = *(const float4*)(tv + c), t1 = *(const float4*)(tv + c + 4);
                float4 a = make_float4(fmaf(x0.x,s0.x,t0.x), fmaf(x0.y,s0.y,t0.y),
                                       fmaf(x0.z,s0.z,t0.z), fmaf(x0.w,s0.w,t0.w));
                float4 b = make_float4(fmaf(x1.x,s1.x,t1.x), fmaf(x1.y,s1.y,t1.y),
                                       fmaf(x1.z,s1.z,t1.z), fmaf(x1.w,s1.w,t1.w));
                val = cvt8(a, b);
            } else {
                val = *(const bf16x8*)((const u16*)A1v + (size_t)row * 128 + (c - 128));
            }
        } else if (AMODE == 3) {
            int c = k0 + sl * 8;
            const float* xp = (const float*)A0v + (size_t)row * 128 + c;
            float4 x0 = *(const float4*)xp, x1 = *(const float4*)(xp + 4);
            float4 s0 = *(const float4*)(sv + c), s1 = *(const float4*)(sv + c + 4);
            float4 t0 = *(const float4*)(tv + c), t1 = *(const float4*)(tv + c + 4);
            float4 a = make_float4(fmaf(x0.x,s0.x,t0.x), fmaf(x0.y,s0.y,t0.y),
                                   fmaf(x0.z,s0.z,t0.z), fmaf(x0.w,s0.w,t0.w));
            float4 b = make_float4(fmaf(x1.x,s1.x,t1.x), fmaf(x1.y,s1.y,t1.y),
                                   fmaf(x1.z,s1.z,t1.z), fmaf(x1.w,s1.w,t1.w));
            val = cvt8(a, b);
        } else { // AMODE 2: Omega gather, all-bf16 except Y
            int seg = k0 >> 7;
            int c = (k0 & 127) + sl * 8;
            if (seg == 0) {
                val = *(const bf16x8*)((const u16*)A0v + (size_t)i0s[r] * 128 + c);
            } else if (seg == 1) {
                val = *(const bf16x8*)((const u16*)A0v + (size_t)i1s[r] * 128 + c);
            } else if (seg == 2) {
                val = *(const bf16x8*)((const u16*)A1v + (size_t)i0s[r] * 128 + c);
            } else if (seg == 3) {
                val = *(const bf16x8*)((const u16*)A1v + (size_t)i1s[r] * 128 + c);
            } else {
                const float* yp = Yp + (size_t)(rowOffset + row) * 32 + sl * 8;
                val = cvt8(*(const float4*)yp, *(const float4*)(yp + 4));
            }
        }
    }
    return val;
}

// ------------- 4-wave MFMA GEMM: tile 128x128, BK=32
template<int AMODE, int ACT, int ACCUM, int OUTBF>
__launch_bounds__(256, 2)
__global__ void gemm_mfma(const void* __restrict__ A0v, const void* __restrict__ A1v,
                          const float* __restrict__ Yp,
                          const int* __restrict__ I0, const int* __restrict__ I1,
                          int rowOffset,
                          const float* __restrict__ sv, const float* __restrict__ tv,
                          const u16* __restrict__ Wb, const float* __restrict__ bias,
                          void* __restrict__ Cv, const float* __restrict__ Cacc,
                          int Mr, int Kd, int Nc, int lda)
{
    __shared__ __align__(16) u16 As[128 * 32];
    __shared__ __align__(16) u16 Bs[128 * 32];
    __shared__ int i0s[128], i1s[128];

    const int t = threadIdx.x;
    const int lane = t & 63;
    const int wid = t >> 6;
    const int wm = wid >> 1, wn = wid & 1;
    const int lb = lane & 15, lh = lane >> 4;
    const int row0 = blockIdx.x * 128;
    const int colb = blockIdx.y * 128;

    if (AMODE == 2) {
        if (t < 128) {
            int r = row0 + t;
            i0s[t] = (r < Mr) ? I0[rowOffset + r] : 0;
        } else {
            int r = row0 + (t - 128);
            i1s[t - 128] = (r < Mr) ? I1[rowOffset + r] : 0;
        }
    }

    f32x4 acc[4][4];
#pragma unroll
    for (int i = 0; i < 4; ++i)
#pragma unroll
        for (int j = 0; j < 4; ++j) acc[i][j] = (f32x4){0.f, 0.f, 0.f, 0.f};

    for (int k0 = 0; k0 < Kd; k0 += 32) {
        __syncthreads();
#pragma unroll
        for (int h = 0; h < 2; ++h) {
            int s = t + h * 256;
            int r = s >> 2, sl = s & 3;
            bf16x8 val = load_a_slot<AMODE>(A0v, A1v, Yp, i0s, i1s, rowOffset, sv, tv,
                                            row0 + r, r, k0, sl, Mr, lda);
            *(bf16x8*)&As[r * 32 + ((sl ^ ((r >> 1) & 3)) << 3)] = val;
        }
#pragma unroll
        for (int h = 0; h < 2; ++h) {
            int s = t + h * 256;
            int n = s >> 2, sl = s & 3;
            bf16x8 val = *(const bf16x8*)(Wb + (size_t)(colb + n) * Kd + k0 + sl * 8);
            *(bf16x8*)&Bs[n * 32 + ((sl ^ ((n >> 1) & 3)) << 3)] = val;
        }
        __syncthreads();
        bf16x8 af[4], bfr[4];
#pragma unroll
        for (int i = 0; i < 4; ++i) {
            int r = wm * 64 + i * 16 + lb;
            af[i] = *(const bf16x8*)&As[r * 32 + ((lh ^ ((r >> 1) & 3)) << 3)];
        }
#pragma unroll
        for (int j = 0; j < 4; ++j) {
            int n = wn * 64 + j * 16 + lb;
            bfr[j] = *(const bf16x8*)&Bs[n * 32 + ((lh ^ ((n >> 1) & 3)) << 3)];
        }
#pragma unroll
        for (int i = 0; i < 4; ++i)
#pragma unroll
            for (int j = 0; j < 4; ++j)
                acc[i][j] = __builtin_amdgcn_mfma_f32_16x16x32_bf16(af[i], bfr[j], acc[i][j], 0, 0, 0);
    }

#pragma unroll
    for (int i = 0; i < 4; ++i) {
#pragma unroll
        for (int j = 0; j < 4; ++j) {
            int col = colb + wn * 64 + j * 16 + lb;
#pragma unroll
            for (int r = 0; r < 4; ++r) {
                int row = row0 + wm * 64 + i * 16 + lh * 4 + r;
                if (row < Mr) {
                    size_t off = (size_t)row * Nc + col;
                    float v = acc[i][j][r];
                    if (ACCUM) v += Cacc[off];
                    if (ACT) v = gelu_erf(v + bias[col]);
                    if (OUTBF) ((u16*)Cv)[off] = f2b(v);
                    else       ((float*)Cv)[off] = v;
                }
            }
        }
    }
}

// ------------- 8-wave MFMA GEMM: tile 128x256, BK=32
template<int AMODE, int ACT, int OUTBF>
__launch_bounds__(512, 4)
__global__ void gemm_wide(const void* __restrict__ A0v, const void* __restrict__ A1v,
                          const float* __restrict__ Yp,
                          const int* __restrict__ I0, const int* __restrict__ I1,
                          int rowOffset,
                          const float* __restrict__ sv, const float* __restrict__ tv,
                          const u16* __restrict__ Wb, const float* __restrict__ bias,
                          void* __restrict__ Cv, int Mr, int Kd, int Nc)
{
    __shared__ __align__(16) u16 As[128 * 32];
    __shared__ __align__(16) u16 Bs[256 * 32];
    __shared__ int i0s[128], i1s[128];

    const int t = threadIdx.x;
    const int lane = t & 63;
    const int wid = t >> 6;
    const int wm = wid >> 2, wn = wid & 3;
    const int lb = lane & 15, lh = lane >> 4;
    const int row0 = blockIdx.x * 128;
    const int colb = blockIdx.y * 256;

    if (AMODE == 2) {
        if (t < 128) {
            int r = row0 + t;
            i0s[t] = (r < Mr) ? I0[rowOffset + r] : 0;
        } else if (t < 256) {
            int r = row0 + (t - 128);
            i1s[t - 128] = (r < Mr) ? I1[rowOffset + r] : 0;
        }
    }

    f32x4 acc[4][4];
#pragma unroll
    for (int i = 0; i < 4; ++i)
#pragma unroll
        for (int j = 0; j < 4; ++j) acc[i][j] = (f32x4){0.f, 0.f, 0.f, 0.f};

    for (int k0 = 0; k0 < Kd; k0 += 32) {
        __syncthreads();
        {
            int r = t >> 2, sl = t & 3;
            bf16x8 val = load_a_slot<AMODE>(A0v, A1v, Yp, i0s, i1s, rowOffset, sv, tv,
                                            row0 + r, r, k0, sl, Mr, 0);
            *(bf16x8*)&As[r * 32 + ((sl ^ ((r >> 1) & 3)) << 3)] = val;
        }
#pragma unroll
        for (int h = 0; h < 2; ++h) {
            int s = t + h * 512;
            int n = s >> 2, sl = s & 3;
            bf16x8 val = *(const bf16x8*)(Wb + (size_t)(colb + n) * Kd + k0 + sl * 8);
            *(bf16x8*)&Bs[n * 32 + ((sl ^ ((n >> 1) & 3)) << 3)] = val;
        }
        __syncthreads();
        bf16x8 af[4], bfr[4];
#pragma unroll
        for (int i = 0; i < 4; ++i) {
            int r = wm * 64 + i * 16 + lb;
            af[i] = *(const bf16x8*)&As[r * 32 + ((lh ^ ((r >> 1) & 3)) << 3)];
        }
#pragma unroll
        for (int j = 0; j < 4; ++j) {
            int n = wn * 64 + j * 16 + lb;
            bfr[j] = *(const bf16x8*)&Bs[n * 32 + ((lh ^ ((n >> 1) & 3)) << 3)];
        }
#pragma unroll
        for (int i = 0; i < 4; ++i)
#pragma unroll
            for (int j = 0; j < 4; ++j)
                acc[i][j] = __builtin_amdgcn_mfma_f32_16x16x32_bf16(af[i], bfr[j], acc[i][j], 0, 0, 0);
    }

#pragma unroll
    for (int i = 0; i < 4; ++i) {
#pragma unroll
        for (int j = 0; j < 4; ++j) {
            int col = colb + wn * 64 + j * 16 + lb;
#pragma unroll
            for (int r = 0; r < 4; ++r) {
                int row = row0 + wm * 64 + i * 16 + lh * 4 + r;
                if (row < Mr) {
                    size_t off = (size_t)row * Nc + col;
                    float v = acc[i][j][r];
                    if (ACT) v = gelu_erf(v + bias[col]);
                    if (OUTBF) ((u16*)Cv)[off] = f2b(v);
                    else       ((float*)Cv)[off] = v;
                }
            }
        }
    }
}

// ------------- edge layer-2 + sigmoid head fused
__launch_bounds__(512, 4)
__global__ void gemm_head(const u16* __restrict__ A0, const u16* __restrict__ Wb,
                          const float* __restrict__ bias, const float* __restrict__ eW,
                          const float* __restrict__ eb,
                          float* __restrict__ outp, int outOffset, int Mr)
{
    __shared__ __align__(16) u16 As[128 * 32];
    __shared__ __align__(16) u16 Bs[256 * 32];
    __shared__ float bls[256], ews[256];
    __shared__ float sred[4][128];

    const int t = threadIdx.x;
    const int lane = t & 63;
    const int wid = t >> 6;
    const int wm = wid >> 2, wn = wid & 3;
    const int lb = lane & 15, lh = lane >> 4;
    const int row0 = blockIdx.x * 128;
    const int Kd = 512;

    if (t < 256) { bls[t] = bias[t]; ews[t] = eW[t]; }

    f32x4 acc[4][4];
#pragma unroll
    for (int i = 0; i < 4; ++i)
#pragma unroll
        for (int j = 0; j < 4; ++j) acc[i][j] = (f32x4){0.f, 0.f, 0.f, 0.f};

    for (int k0 = 0; k0 < Kd; k0 += 32) {
        __syncthreads();
        {
            int r = t >> 2, sl = t & 3;
            int row = row0 + r;
            bf16x8 val = {0,0,0,0,0,0,0,0};
            if (row < Mr) val = *(const bf16x8*)(A0 + (size_t)row * 512 + k0 + sl * 8);
            *(bf16x8*)&As[r * 32 + ((sl ^ ((r >> 1) & 3)) << 3)] = val;
        }
#pragma unroll
        for (int h = 0; h < 2; ++h) {
            int s = t + h * 512;
            int n = s >> 2, sl = s & 3;
            bf16x8 val = *(const bf16x8*)(Wb + (size_t)n * Kd + k0 + sl * 8);
            *(bf16x8*)&Bs[n * 32 + ((sl ^ ((n >> 1) & 3)) << 3)] = val;
        }
        __syncthreads();
        bf16x8 af[4], bfr[4];
#pragma unroll
        for (int i = 0; i < 4; ++i) {
            int r = wm * 64 + i * 16 + lb;
            af[i] = *(const bf16x8*)&As[r * 32 + ((lh ^ ((r >> 1) & 3)) << 3)];
        }
#pragma unroll
        for (int j = 0; j < 4; ++j) {
            int n = wn * 64 + j * 16 + lb;
            bfr[j] = *(const bf16x8*)&Bs[n * 32 + ((lh ^ ((n >> 1) & 3)) << 3)];
        }
#pragma unroll
        for (int i = 0; i < 4; ++i)
#pragma unroll
            for (int j = 0; j < 4; ++j)
                acc[i][j] = __builtin_amdgcn_mfma_f32_16x16x32_bf16(af[i], bfr[j], acc[i][j], 0, 0, 0);
    }

#pragma unroll
    for (int i = 0; i < 4; ++i) {
#pragma unroll
        for (int r = 0; r < 4; ++r) {
            float p = 0.f;
#pragma unroll
            for (int j = 0; j < 4; ++j) {
                int col = wn * 64 + j * 16 + lb;
                p += gelu_erf(acc[i][j][r] + bls[col]) * ews[col];
            }
            p += __shfl_xor(p, 1);
            p += __shfl_xor(p, 2);
            p += __shfl_xor(p, 4);
            p += __shfl_xor(p, 8);
            if (lb == 0) sred[wn][wm * 64 + i * 16 + lh * 4 + r] = p;
        }
    }
    __syncthreads();
    if (t < 128) {
        int row = row0 + t;
        if (row < Mr) {
            float s = sred[0][t] + sred[1][t] + sred[2][t] + sred[3][t] + eb[0];
            outp[outOffset + row] = 1.f / (1.f + expf(-s));
        }
    }
}

// logits = cl @ endW + endB ; softmax over 8 ; one wave per row
__global__ void node_head(const float* __restrict__ cl, const float* __restrict__ Wend,
                          const float* __restrict__ bend, float* __restrict__ out, int m)
{
    __shared__ float WsT[8 * 128];
    __shared__ float bs[8];
    int t = threadIdx.x;
    for (int i = t; i < 1024; i += 256) {
        int k = i >> 3, j = i & 7;
        WsT[j * 128 + k] = Wend[i];
    }
    if (t < 8) bs[t] = bend[t];
    __syncthreads();
    int gid = blockIdx.x * 256 + t;
    int wave = gid >> 6, lane = gid & 63;
    if (wave >= m) return;
    float v0 = cl[(size_t)wave * 128 + lane];
    float v1 = cl[(size_t)wave * 128 + lane + 64];
    float lg[8];
#pragma unroll
    for (int j = 0; j < 8; ++j) {
        float p = v0 * WsT[j * 128 + lane] + v1 * WsT[j * 128 + lane + 64];
#pragma unroll
        for (int o = 32; o; o >>= 1) p += __shfl_down(p, o);
        lg[j] = p;
    }
    if (lane == 0) {
        float mx = -1e30f;
#pragma unroll
        for (int j = 0; j < 8; ++j) { lg[j] += bs[j]; mx = fmaxf(mx, lg[j]); }
        float s = 0.f;
#pragma unroll
        for (int j = 0; j < 8; ++j) { lg[j] = expf(lg[j] - mx); s += lg[j]; }
        float inv = 1.f / s;
#pragma unroll
        for (int j = 0; j < 8; ++j) out[(size_t)wave * 8 + j] = lg[j] * inv;
    }
}

extern "C" void kernel_launch(void* const* d_in, const int* in_sizes, int n_in,
                              void* d_out, int out_size, void* d_ws, size_t ws_size,
                              hipStream_t stream)
{
    const float* X    = (const float*)d_in[0];
    const float* Y    = (const float*)d_in[1];
    const int*   EI   = (const int*)d_in[2];
    const int*   I0   = (const int*)d_in[3];
    const int*   I1   = (const int*)d_in[4];
    const float* bnG  = (const float*)d_in[5];
    const float* bnB  = (const float*)d_in[6];
    const float* Wlin = (const float*)d_in[7];
    const float* blin = (const float*)d_in[8];
    const float* tagWs= (const float*)d_in[9];
    const float* tagB = (const float*)d_in[10];
    const float* nlW0 = (const float*)d_in[11];
    const float* nlb0 = (const float*)d_in[12];
    const float* nlW1 = (const float*)d_in[13];
    const float* nlb1 = (const float*)d_in[14];
    const float* clW  = (const float*)d_in[15];
    const float* clb  = (const float*)d_in[16];
    const float* endW = (const float*)d_in[17];
    const float* endB = (const float*)d_in[18];
    const float* beG  = (const float*)d_in[19];
    const float* beB  = (const float*)d_in[20];
    const float* elW0 = (const float*)d_in[21];
    const float* elb0 = (const float*)d_in[22];
    const float* elW1 = (const float*)d_in[23];
    const float* elb1 = (const float*)d_in[24];
    const float* elEW = (const float*)d_in[25];
    const float* elEb = (const float*)d_in[26];

    const int N = NN, E = NE, P = NP;

    char* w = (char*)d_ws;
    size_t off = 0;
    auto alloc = [&](size_t bytes) -> void* {
        void* p = w + off;
        off += (bytes + 255) & ~(size_t)255;
        return p;
    };

    size_t zeroBytes = (size_t)(544 + 544 + 128 + 128) * 4 + (size_t)4 * N * 4;
    char* zr = (char*)alloc(zeroBytes);
    float* statS = (float*)zr;
    float* statQ = statS + 544;
    float* nodeS = statQ + 544;
    float* nodeQ = nodeS + 128;
    int* cnt    = (int*)(nodeQ + 128);
    int* cursor = cnt + N;
    int* cnt0   = cursor + N;
    int* cnt1   = cnt0 + N;

    int*   indptr = (int*)alloc((size_t)(N + 1) * 4);
    int*   part   = (int*)alloc((size_t)(NB_SCAN + 1) * 4);
    float* dinv   = (float*)alloc((size_t)N * 4);
    int*   csrS   = (int*)alloc((size_t)E * 4);
    float* sNode  = (float*)alloc(128 * 4);
    float* tNode  = (float*)alloc(128 * 4);
    float* sEdge  = (float*)alloc(544 * 4);
    float* tEdge  = (float*)alloc(544 * 4);
    float* b0p    = (float*)alloc(512 * 4);
    u16* Wlinb  = (u16*)alloc((size_t)128 * 128 * 2);
    u16* tagWsb = (u16*)alloc((size_t)7 * 128 * 128 * 2);
    u16* nlW0b  = (u16*)alloc((size_t)256 * 256 * 2);
    u16* nlW1b  = (u16*)alloc((size_t)128 * 256 * 2);
    u16* clWb   = (u16*)alloc((size_t)128 * 128 * 2);
    u16* elW1b  = (u16*)alloc((size_t)256 * 512 * 2);
    u16* W0pb   = (u16*)alloc((size_t)512 * 544 * 2);
    u16*   hA   = (u16*)alloc((size_t)N * 128 * 2);   // h ping / aEmb
    u16*   hB   = (u16*)alloc((size_t)N * 128 * 2);   // h pong / houtb / Xb
    float* outT = (float*)alloc((size_t)N * 128 * 4); // TAG acc / a256+clbuf / o1

    if (ws_size < off) return;

    u16*   aEmb  = hA;
    u16*   houtb = hB;
    float* out_nodes = (float*)d_out;
    float* out_epred = (float*)d_out + (size_t)N * 8;

    hipMemsetAsync(zr, 0, zeroBytes, stream);

    convTB<<<(128*128 + 255)/256, 256, 0, stream>>>(Wlin, Wlinb, 128, 128, 1);
    convTB<<<(7*128*128 + 255)/256, 256, 0, stream>>>(tagWs, tagWsb, 128, 128, 7);
    convTB<<<(256*256 + 255)/256, 256, 0, stream>>>(nlW0, nlW0b, 256, 256, 1);
    convTB<<<(256*128 + 255)/256, 256, 0, stream>>>(nlW1, nlW1b, 256, 128, 1);
    convTB<<<(128*128 + 255)/256, 256, 0, stream>>>(clW, clWb, 128, 128, 1);
    convTB<<<(512*256 + 255)/256, 256, 0, stream>>>(elW1, elW1b, 512, 256, 1);

    col_stats<0><<<1024, 256, 0, stream>>>(X, N, 7, nullptr, nullptr, nodeS, nodeQ, 0, 0);
    bn_finalize<<<1, 128, 0, stream>>>(nodeS, nodeQ, bnG, bnB, sNode, tNode, 128, (float)N, 1e-5f);

    dim3 g1((N + 127) / 128, 1);
    gemm_mfma<3, 1, 0, 1><<<g1, 256, 0, stream>>>(X, nullptr, nullptr, nullptr, nullptr, 0,
                                                  sNode, tNode, Wlinb, blin, hA, nullptr, N, 128, 128, 128);

    hist_add<<<2048, 256, 0, stream>>>(EI + E, E, cnt);
    hist_add2<<<1024, 256, 0, stream>>>(I0, I1, P, cnt0, cnt1);
    scan1<<<NB_SCAN, 1024, 0, stream>>>(cnt, indptr, part, N);
    scan2<<<1, 256, 0, stream>>>(part, NB_SCAN);
    scan3<<<NB_SCAN, 1024, 0, stream>>>(indptr, part, cnt, dinv, N);
    csr_build<<<2048, 256, 0, stream>>>(EI, EI + E, E, indptr, cursor, csrS);

    gemm_mfma<0, 0, 0, 0><<<g1, 256, 0, stream>>>(hA, nullptr, nullptr, nullptr, nullptr, 0,
                                                  nullptr, nullptr, tagWsb, nullptr, outT, nullptr,
                                                  N, 128, 128, 128);
    u16* cur = hA; u16* nxt = hB;
    for (int k = 1; k < KHOPS; ++k) {
        spmm_hop<<<(N * 64 + 255) / 256, 256, 0, stream>>>(cur, nxt, indptr, csrS, dinv);
        gemm_mfma<0, 0, 1, 0><<<g1, 256, 0, stream>>>(nxt, nullptr, nullptr, nullptr, nullptr, 0,
                                                      nullptr, nullptr, tagWsb + (size_t)k*128*128,
                                                      nullptr, outT, outT, N, 128, 128, 128);
        u16* tmp = cur; cur = nxt; nxt = tmp;
    }
    // hop 6 fused: cur=hB holds h5, nxt=hA; spmm hB->hA; GEMM reads hA+outT, writes gelu bf16 -> houtb(hB)
    spmm_hop<<<(N * 64 + 255) / 256, 256, 0, stream>>>(cur, nxt, indptr, csrS, dinv);
    gemm_mfma<0, 1, 1, 1><<<g1, 256, 0, stream>>>(nxt, nullptr, nullptr, nullptr, nullptr, 0,
                                                  nullptr, nullptr, tagWsb + (size_t)KHOPS*128*128,
                                                  tagB, houtb, outT, N, 128, 128, 128);

    u16*   a256  = (u16*)outT;
    float* clbuf = outT;
    {
        dim3 gA((N + 127) / 128, 1);
        gemm_wide<1, 1, 1><<<gA, 512, 0, stream>>>(X, houtb, nullptr, nullptr, nullptr, 0,
                                                   sNode, tNode, nlW0b, nlb0, a256, N, 256, 256);
        dim3 gB((N + 127) / 128, 1);
        gemm_mfma<0, 1, 0, 1><<<gB, 256, 0, stream>>>(a256, nullptr, nullptr, nullptr, nullptr, 0,
                                                      nullptr, nullptr, nlW1b, nlb1, aEmb, nullptr,
                                                      N, 256, 128, 256);
        gemm_mfma<0, 1, 0, 0><<<gB, 256, 0, stream>>>(aEmb, nullptr, nullptr, nullptr, nullptr, 0,
                                                      nullptr, nullptr, clWb, clb, clbuf, nullptr,
                                                      N, 128, 128, 128);
        node_head<<<(N + 3) / 4, 256, 0, stream>>>(clbuf, endW, endB, out_nodes, N);
    }

    // Xb = bf16(X) into hB (houtb dead after node MLP)
    u16* Xb = hB;
    convB<<<2048, 256, 0, stream>>>(X, Xb, N * 128 / 4);

    col_stats<1><<<1024, 256, 0, stream>>>(aEmb, N, 7, cnt0, cnt1, statS, statQ, 0, 128);
    col_stats<1><<<1024, 256, 0, stream>>>(Xb,   N, 7, cnt0, cnt1, statS, statQ, 256, 384);
    col_stats<0><<<1024, 256, 0, stream>>>(Y,    P, 5, nullptr, nullptr, statS, statQ, 512, 0);
    bn_finalize<<<3, 256, 0, stream>>>(statS, statQ, beG, beB, sEdge, tEdge, 544, (float)P, 1.0f);
    fold_wT<<<(512*544 + 255)/256, 256, 0, stream>>>(elW0, sEdge, W0pb);
    fold_b<<<2, 256, 0, stream>>>(elW0, elb0, tEdge, b0p);

    u16* o1 = (u16*)outT;
    for (int pb = 0; pb < P; pb += ECHK) {
        int m = (P - pb < ECHK) ? (P - pb) : ECHK;
        dim3 gA((m + 127) / 128, 2);
        gemm_wide<2, 1, 1><<<gA, 512, 0, stream>>>(aEmb, Xb, Y, I0, I1, pb,
                                                   nullptr, nullptr, W0pb, b0p, o1, m, 544, 512);
        dim3 gB((m + 127) / 128, 1);
        gemm_head<<<gB, 512, 0, stream>>>(o1, elW1b, elb1, elEW, elEb, out_epred, pb, m);
    }
}